// Round 3
// baseline (288.000 us; speedup 1.0000x reference)
//
#include <hip/hip_runtime.h>

#define NPOLY 256
#define VPP   64
#define LCH   32
#define NV    (1 + NPOLY * VPP)
#define LN_EPS 1e-5f

typedef __bf16 bf16x8 __attribute__((ext_vector_type(8)));
typedef float  f32x4  __attribute__((ext_vector_type(4)));

union U4B8 { uint4 u; bf16x8 v; };

__device__ __forceinline__ unsigned f2bf_u(float f) {
    unsigned u = __float_as_uint(f);
    return (u + 0x7FFFu + ((u >> 16) & 1u)) >> 16;   // RNE fp32 -> bf16 bits
}
__device__ __forceinline__ unsigned packbf(float a, float b) {
    return f2bf_u(a) | (f2bf_u(b) << 16);
}

// ---------------------------------------------------------------------------
// prep1: (a) fold Wq/Wk/Wv over the duplicated 128-channel halves of P,
//        (b) pack W0 / W1-top / W2-top into bf16 B-fragment order:
//        frag f, lane L: 8 bf16 = W[k0 + j][ct*16 + (L&15)], k0 = (L>>4)*8 (+ks*32)
// ---------------------------------------------------------------------------
__global__ void vn_prep1(const float* __restrict__ W0, const float* __restrict__ W1,
                         const float* __restrict__ W2,
                         const float* __restrict__ Wq, const float* __restrict__ Wk,
                         const float* __restrict__ Wv,
                         float* __restrict__ Wqf, float* __restrict__ Wkf,
                         float* __restrict__ Wvf, uint4* __restrict__ wpack)
{
    int t = blockIdx.x * 256 + threadIdx.x;
    if (t < 3 * 32768) {
        int which = t >> 15, r = t & 32767;    // r = i*256+c, i<128
        const float* src = which == 0 ? Wq : which == 1 ? Wk : Wv;
        float*       dst = which == 0 ? Wqf : which == 1 ? Wkf : Wvf;
        dst[r] = src[r] + src[r + 128 * 256];
        return;
    }
    t -= 3 * 32768;
    if (t >= 22 * 64) return;
    int f = t >> 6, L = t & 63, q = L >> 4, m = L & 15;
    const float* src; int N, k0, col;
    if (f < 2)      { src = W0; N = 32;  k0 = q * 8;                 col = f * 16 + m; }
    else if (f < 6) { src = W1; N = 64;  k0 = q * 8;                 col = (f - 2) * 16 + m; }
    else { int g = f - 6; src = W2; N = 128; k0 = (g >> 3) * 32 + q * 8; col = (g & 7) * 16 + m; }
    float e[8];
    #pragma unroll
    for (int j = 0; j < 8; j++) e[j] = src[(k0 + j) * N + col];
    uint4 o;
    o.x = packbf(e[0], e[1]); o.y = packbf(e[2], e[3]);
    o.z = packbf(e[4], e[5]); o.w = packbf(e[6], e[7]);
    wpack[f * 64 + L] = o;
}

// ---------------------------------------------------------------------------
// vn_mlp: 256 threads = 4 waves, one poly per wave, PRIVATE LDS slice per
// wave -> no __syncthreads anywhere (within-wave LDS ordering via lgkmcnt).
// MFMA 16x16x32 bf16; C/D: col=lane&15, row=(lane>>4)*4+reg (m89);
// A: A[m=lane&15][k=(lane>>4)*8+j] (m120).
// ---------------------------------------------------------------------------
__global__ __launch_bounds__(256) void vn_mlp(
    const float* __restrict__ data, const uint4* __restrict__ wpack,
    const float* __restrict__ b0, const float* __restrict__ g0, const float* __restrict__ be0,
    const float* __restrict__ W1, const float* __restrict__ b1,
    const float* __restrict__ g1, const float* __restrict__ be1,
    const float* __restrict__ W2, const float* __restrict__ b2,
    const float* __restrict__ g2, const float* __restrict__ be2,
    float* __restrict__ Ph)
{
    __shared__ __align__(16) unsigned short hbuf[4][64 * 72];  // 4 x 9216 B
    __shared__ float fbuf[4][192];                             // per-wave bcast

    const int w = threadIdx.x >> 6;            // wave id in block
    const int L = threadIdx.x & 63, q = L >> 4, m = L & 15;
    const int blk = blockIdx.x * 4 + w;        // poly index: b*NPOLY+p
    const int bb = blk >> 8, pp = blk & 255;

    unsigned short* hb = hbuf[w];
    float* fb = fbuf[w];

    // ---------------- layer 0 : 32 -> 32 ----------------
    const float* rowbase = data + ((size_t)bb * NV + 1 + (size_t)pp * VPP) * LCH;
    bf16x8 A0[4];
    #pragma unroll
    for (int rt = 0; rt < 4; rt++) {
        const float* rp = rowbase + (size_t)(rt * 16 + m) * LCH + q * 8;
        float4 u = *(const float4*)rp;
        float4 v = *(const float4*)(rp + 4);
        if (q == 3) v.w = 0.f;                 // vecs[:, :, -1] = 0
        U4B8 c;
        c.u.x = packbf(u.x, u.y); c.u.y = packbf(u.z, u.w);
        c.u.z = packbf(v.x, v.y); c.u.w = packbf(v.z, v.w);
        A0[rt] = c.v;
    }
    U4B8 t0, t1; t0.u = wpack[0 * 64 + L]; t1.u = wpack[1 * 64 + L];
    float bc0[2] = { b0[m], b0[16 + m] };
    f32x4 acc0[4][2];
    #pragma unroll
    for (int rt = 0; rt < 4; rt++) {
        {
            f32x4 a = { bc0[0], bc0[0], bc0[0], bc0[0] };
            acc0[rt][0] = __builtin_amdgcn_mfma_f32_16x16x32_bf16(A0[rt], t0.v, a, 0, 0, 0);
        }
        {
            f32x4 a = { bc0[1], bc0[1], bc0[1], bc0[1] };
            acc0[rt][1] = __builtin_amdgcn_mfma_f32_16x16x32_bf16(A0[rt], t1.v, a, 0, 0, 0);
        }
    }
    float g0c[2]  = { g0[m],  g0[16 + m]  };
    float be0c[2] = { be0[m], be0[16 + m] };
    float a0mx[2] = { 0.f, 0.f };
    #pragma unroll
    for (int rt = 0; rt < 4; rt++) {
        #pragma unroll
        for (int reg = 0; reg < 4; reg++) {
            float x0 = acc0[rt][0][reg], x1 = acc0[rt][1][reg];
            float rs = x0 + x1, rq = x0 * x0 + x1 * x1;
            #pragma unroll
            for (int s = 1; s < 16; s <<= 1) { rs += __shfl_xor(rs, s, 64); rq += __shfl_xor(rq, s, 64); }
            float mu = rs * (1.f / 32.f);
            float var = rq * (1.f / 32.f) - mu * mu;
            float ri = rsqrtf(var + LN_EPS);
            #pragma unroll
            for (int ct = 0; ct < 2; ct++) {
                float v = fmaxf(fmaf(g0c[ct] * ri, acc0[rt][ct][reg] - mu, be0c[ct]), 0.f);
                acc0[rt][ct][reg] = v;
                a0mx[ct] = fmaxf(a0mx[ct], v);
            }
        }
    }
    #pragma unroll
    for (int ct = 0; ct < 2; ct++) {
        float v = a0mx[ct];
        v = fmaxf(v, __shfl_xor(v, 16, 64));
        v = fmaxf(v, __shfl_xor(v, 32, 64));
        a0mx[ct] = v;
    }
    if (q == 0) { fb[m] = a0mx[0]; fb[16 + m] = a0mx[1]; }
    // uniform part: au1[n=L] = b1[L] + sum_j agg0[j] * W1[32+j][L]
    float au1 = b1[L];
    for (int j = 0; j < 32; j++)
        au1 = fmaf(fb[j], W1[(32 + j) * 64 + L], au1);
    // stage h0 (bf16) for next layer's A-fragments
    #pragma unroll
    for (int rt = 0; rt < 4; rt++)
        #pragma unroll
        for (int reg = 0; reg < 4; reg++) {
            int row = rt * 16 + q * 4 + reg;
            hb[row * 72 + m]      = (unsigned short)f2bf_u(acc0[rt][0][reg]);
            hb[row * 72 + 16 + m] = (unsigned short)f2bf_u(acc0[rt][1][reg]);
        }
    fb[64 + L] = au1;

    // ---------------- layer 1 : 64(per-row 32) -> 64 ----------------
    bf16x8 A1[4];
    #pragma unroll
    for (int rt = 0; rt < 4; rt++) {
        U4B8 c; c.u = *(const uint4*)(hb + (rt * 16 + m) * 72 + q * 8);
        A1[rt] = c.v;
    }
    f32x4 acc1[4][4];
    #pragma unroll
    for (int ct = 0; ct < 4; ct++) {
        U4B8 wv; wv.u = wpack[(2 + ct) * 64 + L];
        float au = fb[64 + ct * 16 + m];
        #pragma unroll
        for (int rt = 0; rt < 4; rt++) {
            f32x4 a = { au, au, au, au };
            acc1[rt][ct] = __builtin_amdgcn_mfma_f32_16x16x32_bf16(A1[rt], wv.v, a, 0, 0, 0);
        }
    }
    float g1c[4], be1c[4];
    #pragma unroll
    for (int ct = 0; ct < 4; ct++) { g1c[ct] = g1[ct * 16 + m]; be1c[ct] = be1[ct * 16 + m]; }
    float a1mx[4] = { 0.f, 0.f, 0.f, 0.f };
    #pragma unroll
    for (int rt = 0; rt < 4; rt++) {
        #pragma unroll
        for (int reg = 0; reg < 4; reg++) {
            float rs = 0.f, rq = 0.f;
            #pragma unroll
            for (int ct = 0; ct < 4; ct++) { float x = acc1[rt][ct][reg]; rs += x; rq += x * x; }
            #pragma unroll
            for (int s = 1; s < 16; s <<= 1) { rs += __shfl_xor(rs, s, 64); rq += __shfl_xor(rq, s, 64); }
            float mu = rs * (1.f / 64.f);
            float var = rq * (1.f / 64.f) - mu * mu;
            float ri = rsqrtf(var + LN_EPS);
            #pragma unroll
            for (int ct = 0; ct < 4; ct++) {
                float v = fmaxf(fmaf(g1c[ct] * ri, acc1[rt][ct][reg] - mu, be1c[ct]), 0.f);
                acc1[rt][ct][reg] = v;
                a1mx[ct] = fmaxf(a1mx[ct], v);
            }
        }
    }
    #pragma unroll
    for (int ct = 0; ct < 4; ct++) {
        float v = a1mx[ct];
        v = fmaxf(v, __shfl_xor(v, 16, 64));
        v = fmaxf(v, __shfl_xor(v, 32, 64));
        a1mx[ct] = v;
    }
    if (q == 0) {
        #pragma unroll
        for (int ct = 0; ct < 4; ct++) fb[ct * 16 + m] = a1mx[ct];
    }
    float au2a = b2[L], au2b = b2[64 + L];
    for (int j = 0; j < 64; j++) {
        float av = fb[j];
        au2a = fmaf(av, W2[(64 + j) * 128 + L],      au2a);
        au2b = fmaf(av, W2[(64 + j) * 128 + 64 + L], au2b);
    }
    #pragma unroll
    for (int rt = 0; rt < 4; rt++)
        #pragma unroll
        for (int reg = 0; reg < 4; reg++) {
            int row = rt * 16 + q * 4 + reg;
            #pragma unroll
            for (int ct = 0; ct < 4; ct++)
                hb[row * 72 + ct * 16 + m] = (unsigned short)f2bf_u(acc1[rt][ct][reg]);
        }
    fb[64 + L] = au2a; fb[128 + L] = au2b;

    // ---------------- layer 2 : 128(per-row 64) -> 128 ----------------
    bf16x8 A2[4][2];
    #pragma unroll
    for (int rt = 0; rt < 4; rt++)
        #pragma unroll
        for (int ks = 0; ks < 2; ks++) {
            U4B8 c; c.u = *(const uint4*)(hb + (rt * 16 + m) * 72 + ks * 32 + q * 8);
            A2[rt][ks] = c.v;
        }
    f32x4 acc2[8][4];
    #pragma unroll
    for (int ct = 0; ct < 8; ct++) {
        U4B8 wa, wb;
        wa.u = wpack[(6 + ct) * 64 + L];
        wb.u = wpack[(14 + ct) * 64 + L];
        float au = fb[64 + ct * 16 + m];
        #pragma unroll
        for (int rt = 0; rt < 4; rt++) {
            f32x4 a = { au, au, au, au };
            a = __builtin_amdgcn_mfma_f32_16x16x32_bf16(A2[rt][0], wa.v, a, 0, 0, 0);
            a = __builtin_amdgcn_mfma_f32_16x16x32_bf16(A2[rt][1], wb.v, a, 0, 0, 0);
            acc2[ct][rt] = a;
        }
    }
    float g2c[8], be2c[8];
    #pragma unroll
    for (int ct = 0; ct < 8; ct++) { g2c[ct] = g2[ct * 16 + m]; be2c[ct] = be2[ct * 16 + m]; }
    float m2[8] = { 0.f, 0.f, 0.f, 0.f, 0.f, 0.f, 0.f, 0.f };
    #pragma unroll
    for (int rt = 0; rt < 4; rt++) {
        #pragma unroll
        for (int reg = 0; reg < 4; reg++) {
            float rs = 0.f, rq = 0.f;
            #pragma unroll
            for (int ct = 0; ct < 8; ct++) { float x = acc2[ct][rt][reg]; rs += x; rq += x * x; }
            #pragma unroll
            for (int s = 1; s < 16; s <<= 1) { rs += __shfl_xor(rs, s, 64); rq += __shfl_xor(rq, s, 64); }
            float mu = rs * (1.f / 128.f);
            float var = rq * (1.f / 128.f) - mu * mu;
            float ri = rsqrtf(var + LN_EPS);
            #pragma unroll
            for (int ct = 0; ct < 8; ct++) {
                float v = fmaxf(fmaf(g2c[ct] * ri, acc2[ct][rt][reg] - mu, be2c[ct]), 0.f);
                m2[ct] = fmaxf(m2[ct], v);
            }
        }
    }
    #pragma unroll
    for (int ct = 0; ct < 8; ct++) {
        float v = m2[ct];
        v = fmaxf(v, __shfl_xor(v, 16, 64));
        v = fmaxf(v, __shfl_xor(v, 32, 64));
        m2[ct] = v;
    }
    // lane L stores cols L and 64+L:  col = (q or 4+q)*16 + m
    float v1 = q == 0 ? m2[0] : q == 1 ? m2[1] : q == 2 ? m2[2] : m2[3];
    float v2 = q == 0 ? m2[4] : q == 1 ? m2[5] : q == 2 ? m2[6] : m2[7];
    float* op = Ph + (size_t)blk * 128;
    op[L] = v1; op[64 + L] = v2;
}

// ---------------------------------------------------------------------------
// vn_attn: per-batch tail on folded matrices (prep2 folded in here).
//   q = pah @ Wqf + bq ; tts[j] = q . Wkf[j] ; scores = Ph . tts / 16 ;
//   softmax ; out = (sum att*Ph) @ Wvf + bv
// ---------------------------------------------------------------------------
__global__ __launch_bounds__(256) void vn_attn(
    const float* __restrict__ data, const float* __restrict__ Ph,
    const float* __restrict__ Wqf, const float* __restrict__ Wkf,
    const float* __restrict__ Wvf, const float* __restrict__ bq,
    const float* __restrict__ bv, float* __restrict__ out)
{
    __shared__ float pah[128], qs[256], tts[128], sc[256], pb[128], red[8];
    const int b = blockIdx.x, tid = threadIdx.x, lane = tid & 63, wave = tid >> 6;
    const float* PhB = Ph + (size_t)b * NPOLY * 128;
    const int agent = (int)data[(size_t)b * NV * LCH];

    if (tid < 128) pah[tid] = PhB[(size_t)agent * 128 + tid];
    __syncthreads();
    // q[c] = bq[c] + sum_i pah[i] * Wqf[i][c]   (coalesced across tid)
    {
        float a = bq[tid];
        for (int i = 0; i < 128; i++) a = fmaf(pah[i], Wqf[i * 256 + tid], a);
        qs[tid] = a;
    }
    __syncthreads();
    // tts[j] = q . Wkf[j]  (wave-cooperative, coalesced)
    for (int jj = 0; jj < 32; jj++) {
        const int j = wave * 32 + jj;
        const float* wr = Wkf + (size_t)j * 256;
        float p = wr[lane] * qs[lane];
        p = fmaf(wr[ 64 + lane], qs[ 64 + lane], p);
        p = fmaf(wr[128 + lane], qs[128 + lane], p);
        p = fmaf(wr[192 + lane], qs[192 + lane], p);
        #pragma unroll
        for (int s = 1; s < 64; s <<= 1) p += __shfl_xor(p, s, 64);
        if (lane == 0) tts[j] = p;
    }
    __syncthreads();
    for (int pi = 0; pi < 64; pi++) {
        const int p = wave * 64 + pi;
        const float* pr = PhB + (size_t)p * 128;
        float s = pr[lane] * tts[lane];
        s = fmaf(pr[64 + lane], tts[64 + lane], s);
        #pragma unroll
        for (int st = 1; st < 64; st <<= 1) s += __shfl_xor(s, st, 64);
        if (lane == 0) sc[p] = s * 0.0625f;
    }
    __syncthreads();
    float sv = sc[tid];
    float mx = sv;
    #pragma unroll
    for (int s = 1; s < 64; s <<= 1) mx = fmaxf(mx, __shfl_xor(mx, s, 64));
    if (lane == 0) red[wave] = mx;
    __syncthreads();
    mx = fmaxf(fmaxf(red[0], red[1]), fmaxf(red[2], red[3]));
    float e = expf(sv - mx);
    float sm = e;
    #pragma unroll
    for (int s = 1; s < 64; s <<= 1) sm += __shfl_xor(sm, s, 64);
    if (lane == 0) red[4 + wave] = sm;
    __syncthreads();
    const float tot = red[4] + red[5] + red[6] + red[7];
    sc[tid] = e / tot;
    __syncthreads();
    if (tid < 128) {
        float a = 0.f;
        for (int p = 0; p < 256; p++) a = fmaf(sc[p], PhB[(size_t)p * 128 + tid], a);
        pb[tid] = a;
    }
    __syncthreads();
    float o = bv[tid];
    for (int j = 0; j < 128; j++) o = fmaf(pb[j], Wvf[j * 256 + tid], o);
    out[(size_t)b * 256 + tid] = o;
}

extern "C" void kernel_launch(void* const* d_in, const int* in_sizes, int n_in,
                              void* d_out, int out_size, void* d_ws, size_t ws_size,
                              hipStream_t stream)
{
    const float* data = (const float*)d_in[0];
    const float* W0 = (const float*)d_in[1];
    const float* b0 = (const float*)d_in[2];
    const float* g0 = (const float*)d_in[3];
    const float* be0= (const float*)d_in[4];
    const float* W1 = (const float*)d_in[5];
    const float* b1 = (const float*)d_in[6];
    const float* g1 = (const float*)d_in[7];
    const float* be1= (const float*)d_in[8];
    const float* W2 = (const float*)d_in[9];
    const float* b2 = (const float*)d_in[10];
    const float* g2 = (const float*)d_in[11];
    const float* be2= (const float*)d_in[12];
    const float* Wq = (const float*)d_in[13];
    const float* bq = (const float*)d_in[14];
    const float* Wk = (const float*)d_in[15];
    const float* bk = (const float*)d_in[16];
    const float* Wv = (const float*)d_in[17];
    const float* bv = (const float*)d_in[18];
    (void)bk;

    char* wsb = (char*)d_ws;
    float* Ph    = (float*)(wsb);                  // 4 MB
    float* Wqf   = (float*)(wsb + 4194304);        // 128 KB
    float* Wkf   = (float*)(wsb + 4325376);        // 128 KB
    float* Wvf   = (float*)(wsb + 4456448);        // 128 KB
    uint4* wpack = (uint4*)(wsb + 4587520);        // 22 KB

    vn_prep1<<<390, 256, 0, stream>>>(W0, W1, W2, Wq, Wk, Wv, Wqf, Wkf, Wvf, wpack);
    vn_mlp<<<2048, 256, 0, stream>>>(data, wpack,
                                     b0, g0, be0,
                                     W1, b1, g1, be1,
                                     W2, b2, g2, be2, Ph);
    vn_attn<<<32, 256, 0, stream>>>(data, Ph, Wqf, Wkf, Wvf, bq, bv, (float*)d_out);
}

// Round 4
// 260.188 us; speedup vs baseline: 1.1069x; 1.1069x over previous
//
#include <hip/hip_runtime.h>

#define NPOLY 256
#define VPP   64
#define LCH   32
#define NV    (1 + NPOLY * VPP)
#define LN_EPS 1e-5f

typedef __bf16 bf16x8 __attribute__((ext_vector_type(8)));
typedef float  f32x4  __attribute__((ext_vector_type(4)));

union U4B8 { uint4 u; bf16x8 v; };

__device__ __forceinline__ unsigned f2bf_u(float f) {
    unsigned u = __float_as_uint(f);
    return (u + 0x7FFFu + ((u >> 16) & 1u)) >> 16;   // RNE fp32 -> bf16 bits
}
__device__ __forceinline__ unsigned packbf(float a, float b) {
    return f2bf_u(a) | (f2bf_u(b) << 16);
}

// ---------------------------------------------------------------------------
// prep1: (a) fold Wq/Wk/Wv over the duplicated 128-channel halves of P,
//        (b) pack W0 / W1-top / W2-top into bf16 B-fragment order:
//        frag f, lane L: 8 bf16 = W[k0 + j][ct*16 + (L&15)], k0 = (L>>4)*8 (+ks*32)
// ---------------------------------------------------------------------------
__global__ void vn_prep1(const float* __restrict__ W0, const float* __restrict__ W1,
                         const float* __restrict__ W2,
                         const float* __restrict__ Wq, const float* __restrict__ Wk,
                         const float* __restrict__ Wv,
                         float* __restrict__ Wqf, float* __restrict__ Wkf,
                         float* __restrict__ Wvf, uint4* __restrict__ wpack)
{
    int t = blockIdx.x * 256 + threadIdx.x;
    if (t < 3 * 32768) {
        int which = t >> 15, r = t & 32767;    // r = i*256+c, i<128
        const float* src = which == 0 ? Wq : which == 1 ? Wk : Wv;
        float*       dst = which == 0 ? Wqf : which == 1 ? Wkf : Wvf;
        dst[r] = src[r] + src[r + 128 * 256];
        return;
    }
    t -= 3 * 32768;
    if (t >= 22 * 64) return;
    int f = t >> 6, L = t & 63, q = L >> 4, m = L & 15;
    const float* src; int N, k0, col;
    if (f < 2)      { src = W0; N = 32;  k0 = q * 8;                 col = f * 16 + m; }
    else if (f < 6) { src = W1; N = 64;  k0 = q * 8;                 col = (f - 2) * 16 + m; }
    else { int g = f - 6; src = W2; N = 128; k0 = (g >> 3) * 32 + q * 8; col = (g & 7) * 16 + m; }
    float e[8];
    #pragma unroll
    for (int j = 0; j < 8; j++) e[j] = src[(k0 + j) * N + col];
    uint4 o;
    o.x = packbf(e[0], e[1]); o.y = packbf(e[2], e[3]);
    o.z = packbf(e[4], e[5]); o.w = packbf(e[6], e[7]);
    wpack[f * 64 + L] = o;
}

// ---------------------------------------------------------------------------
// vn_mlp: ONE POLY PER BLOCK, 4 waves, each wave owns a 16-row slice.
// Per-wave acc tile in layer 2 is only 1x8 f32x4 = 32 regs -> target <=128
// combined VGPR+AGPR so 4 waves/SIMD fit. Cross-wave col-max via LDS
// partials + 3 barriers. hbuf rows are wave-private (no barrier needed).
// MFMA 16x16x32 bf16; C/D: col=lane&15, row=(lane>>4)*4+reg (m89);
// A: A[m=lane&15][k=(lane>>4)*8+j] (m120).
// ---------------------------------------------------------------------------
__global__ __launch_bounds__(256, 4) void vn_mlp(
    const float* __restrict__ data, const uint4* __restrict__ wpack,
    const float* __restrict__ b0, const float* __restrict__ g0, const float* __restrict__ be0,
    const float* __restrict__ W1, const float* __restrict__ b1,
    const float* __restrict__ g1, const float* __restrict__ be1,
    const float* __restrict__ W2, const float* __restrict__ b2,
    const float* __restrict__ g2, const float* __restrict__ be2,
    float* __restrict__ Ph)
{
    __shared__ __align__(16) unsigned short hbuf[64 * 72];  // 9216 B, rows wave-private
    __shared__ float agg0p[4][32];
    __shared__ float agg1p[4][64];
    __shared__ float agg2p[4][128];
    __shared__ float aub1[64];
    __shared__ float aub2[128];

    const int tid = threadIdx.x;
    const int w = tid >> 6, L = tid & 63, q = L >> 4, m = L & 15;
    const int blk = blockIdx.x;              // b*NPOLY + p
    const int bb = blk >> 8, pp = blk & 255;

    // ---------------- layer 0 : 32 -> 32 (rows w*16 .. w*16+15) ----------
    bf16x8 A0;
    {
        const float* rp = data + ((size_t)bb * NV + 1 + (size_t)pp * VPP + w * 16 + m) * LCH + q * 8;
        float4 u = *(const float4*)rp;
        float4 v = *(const float4*)(rp + 4);
        if (q == 3) v.w = 0.f;               // vecs[:, :, -1] = 0
        U4B8 c;
        c.u.x = packbf(u.x, u.y); c.u.y = packbf(u.z, u.w);
        c.u.z = packbf(v.x, v.y); c.u.w = packbf(v.z, v.w);
        A0 = c.v;
    }
    f32x4 acc0[2];
    {
        U4B8 t0, t1; t0.u = wpack[0 * 64 + L]; t1.u = wpack[1 * 64 + L];
        float b00 = b0[m], b01 = b0[16 + m];
        f32x4 ai0 = { b00, b00, b00, b00 };
        f32x4 ai1 = { b01, b01, b01, b01 };
        acc0[0] = __builtin_amdgcn_mfma_f32_16x16x32_bf16(A0, t0.v, ai0, 0, 0, 0);
        acc0[1] = __builtin_amdgcn_mfma_f32_16x16x32_bf16(A0, t1.v, ai1, 0, 0, 0);
    }
    {
        float g0c[2]  = { g0[m],  g0[16 + m]  };
        float be0c[2] = { be0[m], be0[16 + m] };
        float mx[2] = { 0.f, 0.f };
        #pragma unroll
        for (int reg = 0; reg < 4; reg++) {
            float x0 = acc0[0][reg], x1 = acc0[1][reg];
            float rs = x0 + x1, rq = x0 * x0 + x1 * x1;
            #pragma unroll
            for (int s = 1; s < 16; s <<= 1) { rs += __shfl_xor(rs, s, 64); rq += __shfl_xor(rq, s, 64); }
            float mu = rs * (1.f / 32.f);
            float var = rq * (1.f / 32.f) - mu * mu;
            float ri = rsqrtf(var + LN_EPS);
            #pragma unroll
            for (int ct = 0; ct < 2; ct++) {
                float v = fmaxf(fmaf(g0c[ct] * ri, acc0[ct][reg] - mu, be0c[ct]), 0.f);
                acc0[ct][reg] = v;
                mx[ct] = fmaxf(mx[ct], v);
            }
        }
        #pragma unroll
        for (int ct = 0; ct < 2; ct++) {
            float v = mx[ct];
            v = fmaxf(v, __shfl_xor(v, 16, 64));
            v = fmaxf(v, __shfl_xor(v, 32, 64));
            mx[ct] = v;
        }
        if (q == 0) { agg0p[w][m] = mx[0]; agg0p[w][16 + m] = mx[1]; }
        // stage h0 (wave-private rows)
        #pragma unroll
        for (int reg = 0; reg < 4; reg++) {
            int row = w * 16 + q * 4 + reg;
            hbuf[row * 72 + m]      = (unsigned short)f2bf_u(acc0[0][reg]);
            hbuf[row * 72 + 16 + m] = (unsigned short)f2bf_u(acc0[1][reg]);
        }
    }
    __syncthreads();

    // au1[L] = b1[L] + sum_j agg0[j] * W1[32+j][L]  (redundant per wave, identical)
    {
        float au1 = b1[L];
        for (int j = 0; j < 32; j++) {
            float a = fmaxf(fmaxf(agg0p[0][j], agg0p[1][j]), fmaxf(agg0p[2][j], agg0p[3][j]));
            au1 = fmaf(a, W1[(32 + j) * 64 + L], au1);
        }
        aub1[L] = au1;   // all waves write identical values
    }

    // ---------------- layer 1 : 64(per-row 32) -> 64 ----------------------
    bf16x8 A1;
    { U4B8 c; c.u = *(const uint4*)(hbuf + (w * 16 + m) * 72 + q * 8); A1 = c.v; }
    f32x4 acc1[4];
    #pragma unroll
    for (int ct = 0; ct < 4; ct++) {
        U4B8 wv; wv.u = wpack[(2 + ct) * 64 + L];
        float au = aub1[ct * 16 + m];
        f32x4 ai = { au, au, au, au };
        acc1[ct] = __builtin_amdgcn_mfma_f32_16x16x32_bf16(A1, wv.v, ai, 0, 0, 0);
    }
    {
        float g1c[4], be1c[4];
        #pragma unroll
        for (int ct = 0; ct < 4; ct++) { g1c[ct] = g1[ct * 16 + m]; be1c[ct] = be1[ct * 16 + m]; }
        float mx[4] = { 0.f, 0.f, 0.f, 0.f };
        #pragma unroll
        for (int reg = 0; reg < 4; reg++) {
            float rs = 0.f, rq = 0.f;
            #pragma unroll
            for (int ct = 0; ct < 4; ct++) { float x = acc1[ct][reg]; rs += x; rq += x * x; }
            #pragma unroll
            for (int s = 1; s < 16; s <<= 1) { rs += __shfl_xor(rs, s, 64); rq += __shfl_xor(rq, s, 64); }
            float mu = rs * (1.f / 64.f);
            float var = rq * (1.f / 64.f) - mu * mu;
            float ri = rsqrtf(var + LN_EPS);
            #pragma unroll
            for (int ct = 0; ct < 4; ct++) {
                float v = fmaxf(fmaf(g1c[ct] * ri, acc1[ct][reg] - mu, be1c[ct]), 0.f);
                acc1[ct][reg] = v;
                mx[ct] = fmaxf(mx[ct], v);
            }
        }
        #pragma unroll
        for (int ct = 0; ct < 4; ct++) {
            float v = mx[ct];
            v = fmaxf(v, __shfl_xor(v, 16, 64));
            v = fmaxf(v, __shfl_xor(v, 32, 64));
            mx[ct] = v;
        }
        if (q == 0) {
            #pragma unroll
            for (int ct = 0; ct < 4; ct++) agg1p[w][ct * 16 + m] = mx[ct];
        }
        #pragma unroll
        for (int reg = 0; reg < 4; reg++) {
            int row = w * 16 + q * 4 + reg;
            #pragma unroll
            for (int ct = 0; ct < 4; ct++)
                hbuf[row * 72 + ct * 16 + m] = (unsigned short)f2bf_u(acc1[ct][reg]);
        }
    }
    __syncthreads();

    // au2 for cols L and 64+L (redundant per wave, identical)
    {
        float au2a = b2[L], au2b = b2[64 + L];
        for (int j = 0; j < 64; j++) {
            float a = fmaxf(fmaxf(agg1p[0][j], agg1p[1][j]), fmaxf(agg1p[2][j], agg1p[3][j]));
            au2a = fmaf(a, W2[(64 + j) * 128 + L],      au2a);
            au2b = fmaf(a, W2[(64 + j) * 128 + 64 + L], au2b);
        }
        aub2[L] = au2a; aub2[64 + L] = au2b;
    }

    // ---------------- layer 2 : 128(per-row 64) -> 128 ---------------------
    bf16x8 A2[2];
    #pragma unroll
    for (int ks = 0; ks < 2; ks++) {
        U4B8 c; c.u = *(const uint4*)(hbuf + (w * 16 + m) * 72 + ks * 32 + q * 8);
        A2[ks] = c.v;
    }
    f32x4 acc2[8];
    #pragma unroll
    for (int ct = 0; ct < 8; ct++) {
        U4B8 wa, wb;
        wa.u = wpack[(6 + ct) * 64 + L];
        wb.u = wpack[(14 + ct) * 64 + L];
        float au = aub2[ct * 16 + m];
        f32x4 ai = { au, au, au, au };
        ai = __builtin_amdgcn_mfma_f32_16x16x32_bf16(A2[0], wa.v, ai, 0, 0, 0);
        ai = __builtin_amdgcn_mfma_f32_16x16x32_bf16(A2[1], wb.v, ai, 0, 0, 0);
        acc2[ct] = ai;
    }
    {
        float g2c[8], be2c[8];
        #pragma unroll
        for (int ct = 0; ct < 8; ct++) { g2c[ct] = g2[ct * 16 + m]; be2c[ct] = be2[ct * 16 + m]; }
        float mx[8] = { 0.f, 0.f, 0.f, 0.f, 0.f, 0.f, 0.f, 0.f };
        #pragma unroll
        for (int reg = 0; reg < 4; reg++) {
            float rs = 0.f, rq = 0.f;
            #pragma unroll
            for (int ct = 0; ct < 8; ct++) { float x = acc2[ct][reg]; rs += x; rq += x * x; }
            #pragma unroll
            for (int s = 1; s < 16; s <<= 1) { rs += __shfl_xor(rs, s, 64); rq += __shfl_xor(rq, s, 64); }
            float mu = rs * (1.f / 128.f);
            float var = rq * (1.f / 128.f) - mu * mu;
            float ri = rsqrtf(var + LN_EPS);
            #pragma unroll
            for (int ct = 0; ct < 8; ct++) {
                float v = fmaxf(fmaf(g2c[ct] * ri, acc2[ct][reg] - mu, be2c[ct]), 0.f);
                mx[ct] = fmaxf(mx[ct], v);
            }
        }
        #pragma unroll
        for (int ct = 0; ct < 8; ct++) {
            float v = mx[ct];
            v = fmaxf(v, __shfl_xor(v, 16, 64));
            v = fmaxf(v, __shfl_xor(v, 32, 64));
            mx[ct] = v;
        }
        if (q == 0) {
            #pragma unroll
            for (int ct = 0; ct < 8; ct++) agg2p[w][ct * 16 + m] = mx[ct];
        }
    }
    __syncthreads();

    // final col-max across waves; wave w writes cols [w*32, w*32+32)
    if (L < 32) {
        int col = w * 32 + L;
        float v = fmaxf(fmaxf(agg2p[0][col], agg2p[1][col]),
                        fmaxf(agg2p[2][col], agg2p[3][col]));
        Ph[(size_t)blk * 128 + col] = v;
    }
}

// ---------------------------------------------------------------------------
// vn_attn: per-batch tail on folded matrices.
//   q = pah @ Wqf + bq ; tts[j] = q . Wkf[j] ; scores = Ph . tts / 16 ;
//   softmax ; out = (sum att*Ph) @ Wvf + bv
// ---------------------------------------------------------------------------
__global__ __launch_bounds__(256) void vn_attn(
    const float* __restrict__ data, const float* __restrict__ Ph,
    const float* __restrict__ Wqf, const float* __restrict__ Wkf,
    const float* __restrict__ Wvf, const float* __restrict__ bq,
    const float* __restrict__ bv, float* __restrict__ out)
{
    __shared__ float pah[128], qs[256], tts[128], sc[256], pb[128], red[8];
    const int b = blockIdx.x, tid = threadIdx.x, lane = tid & 63, wave = tid >> 6;
    const float* PhB = Ph + (size_t)b * NPOLY * 128;
    const int agent = (int)data[(size_t)b * NV * LCH];

    if (tid < 128) pah[tid] = PhB[(size_t)agent * 128 + tid];
    __syncthreads();
    {
        float a = bq[tid];
        for (int i = 0; i < 128; i++) a = fmaf(pah[i], Wqf[i * 256 + tid], a);
        qs[tid] = a;
    }
    __syncthreads();
    for (int jj = 0; jj < 32; jj++) {
        const int j = wave * 32 + jj;
        const float* wr = Wkf + (size_t)j * 256;
        float p = wr[lane] * qs[lane];
        p = fmaf(wr[ 64 + lane], qs[ 64 + lane], p);
        p = fmaf(wr[128 + lane], qs[128 + lane], p);
        p = fmaf(wr[192 + lane], qs[192 + lane], p);
        #pragma unroll
        for (int s = 1; s < 64; s <<= 1) p += __shfl_xor(p, s, 64);
        if (lane == 0) tts[j] = p;
    }
    __syncthreads();
    for (int pi = 0; pi < 64; pi++) {
        const int p = wave * 64 + pi;
        const float* pr = PhB + (size_t)p * 128;
        float s = pr[lane] * tts[lane];
        s = fmaf(pr[64 + lane], tts[64 + lane], s);
        #pragma unroll
        for (int st = 1; st < 64; st <<= 1) s += __shfl_xor(s, st, 64);
        if (lane == 0) sc[p] = s * 0.0625f;
    }
    __syncthreads();
    float sv = sc[tid];
    float mx = sv;
    #pragma unroll
    for (int s = 1; s < 64; s <<= 1) mx = fmaxf(mx, __shfl_xor(mx, s, 64));
    if (lane == 0) red[wave] = mx;
    __syncthreads();
    mx = fmaxf(fmaxf(red[0], red[1]), fmaxf(red[2], red[3]));
    float e = expf(sv - mx);
    float sm = e;
    #pragma unroll
    for (int s = 1; s < 64; s <<= 1) sm += __shfl_xor(sm, s, 64);
    if (lane == 0) red[4 + wave] = sm;
    __syncthreads();
    const float tot = red[4] + red[5] + red[6] + red[7];
    sc[tid] = e / tot;
    __syncthreads();
    if (tid < 128) {
        float a = 0.f;
        for (int p = 0; p < 256; p++) a = fmaf(sc[p], PhB[(size_t)p * 128 + tid], a);
        pb[tid] = a;
    }
    __syncthreads();
    float o = bv[tid];
    for (int j = 0; j < 128; j++) o = fmaf(pb[j], Wvf[j * 256 + tid], o);
    out[(size_t)b * 256 + tid] = o;
}

extern "C" void kernel_launch(void* const* d_in, const int* in_sizes, int n_in,
                              void* d_out, int out_size, void* d_ws, size_t ws_size,
                              hipStream_t stream)
{
    const float* data = (const float*)d_in[0];
    const float* W0 = (const float*)d_in[1];
    const float* b0 = (const float*)d_in[2];
    const float* g0 = (const float*)d_in[3];
    const float* be0= (const float*)d_in[4];
    const float* W1 = (const float*)d_in[5];
    const float* b1 = (const float*)d_in[6];
    const float* g1 = (const float*)d_in[7];
    const float* be1= (const float*)d_in[8];
    const float* W2 = (const float*)d_in[9];
    const float* b2 = (const float*)d_in[10];
    const float* g2 = (const float*)d_in[11];
    const float* be2= (const float*)d_in[12];
    const float* Wq = (const float*)d_in[13];
    const float* bq = (const float*)d_in[14];
    const float* Wk = (const float*)d_in[15];
    const float* bk = (const float*)d_in[16];
    const float* Wv = (const float*)d_in[17];
    const float* bv = (const float*)d_in[18];
    (void)bk;

    char* wsb = (char*)d_ws;
    float* Ph    = (float*)(wsb);                  // 4 MB
    float* Wqf   = (float*)(wsb + 4194304);        // 128 KB
    float* Wkf   = (float*)(wsb + 4325376);        // 128 KB
    float* Wvf   = (float*)(wsb + 4456448);        // 128 KB
    uint4* wpack = (uint4*)(wsb + 4587520);        // 22 KB

    vn_prep1<<<390, 256, 0, stream>>>(W0, W1, W2, Wq, Wk, Wv, Wqf, Wkf, Wvf, wpack);
    vn_mlp<<<8192, 256, 0, stream>>>(data, wpack,
                                     b0, g0, be0,
                                     W1, b1, g1, be1,
                                     W2, b2, g2, be2, Ph);
    vn_attn<<<32, 256, 0, stream>>>(data, Ph, Wqf, Wkf, Wvf, bq, bv, (float*)d_out);
}

// Round 5
// 253.852 us; speedup vs baseline: 1.1345x; 1.0250x over previous
//
#include <hip/hip_runtime.h>

#define NPOLY 256
#define VPP   64
#define LCH   32
#define NV    (1 + NPOLY * VPP)
#define LN_EPS 1e-5f

typedef __bf16 bf16x8 __attribute__((ext_vector_type(8)));
typedef float  f32x4  __attribute__((ext_vector_type(4)));

union U4B8 { uint4 u; bf16x8 v; };

__device__ __forceinline__ unsigned f2bf_u(float f) {
    unsigned u = __float_as_uint(f);
    return (u + 0x7FFFu + ((u >> 16) & 1u)) >> 16;   // RNE fp32 -> bf16 bits
}
__device__ __forceinline__ unsigned packbf(float a, float b) {
    return f2bf_u(a) | (f2bf_u(b) << 16);
}

// ---------------------------------------------------------------------------
// prep1: (a) fold Wq/Wk/Wv over the duplicated 128-channel halves of P,
//        (b) pack weights into bf16 B-fragment order:
//        frag f, lane L: 8 bf16 = W[k0 + j][col], col = ct*16 + (L&15),
//        k0 = (L>>4)*8 (+32*ks) (+row offset for bottom halves).
//        Frags: 0-1 W0 | 2-5 W1top | 6-21 W2top(ks,ct) | 22-25 W1bot |
//               26-41 W2bot(ks,ct)
// ---------------------------------------------------------------------------
__global__ void vn_prep1(const float* __restrict__ W0, const float* __restrict__ W1,
                         const float* __restrict__ W2,
                         const float* __restrict__ Wq, const float* __restrict__ Wk,
                         const float* __restrict__ Wv,
                         float* __restrict__ Wqf, float* __restrict__ Wkf,
                         float* __restrict__ Wvf, uint4* __restrict__ wpack)
{
    int t = blockIdx.x * 256 + threadIdx.x;
    if (t < 3 * 32768) {
        int which = t >> 15, r = t & 32767;    // r = i*256+c, i<128
        const float* src = which == 0 ? Wq : which == 1 ? Wk : Wv;
        float*       dst = which == 0 ? Wqf : which == 1 ? Wkf : Wvf;
        dst[r] = src[r] + src[r + 128 * 256];
        return;
    }
    t -= 3 * 32768;
    if (t >= 42 * 64) return;
    int f = t >> 6, L = t & 63, q = L >> 4, m = L & 15;
    const float* src; int N, k0, col;
    if (f < 2)       { src = W0; N = 32;  k0 = q * 8;                      col = f * 16 + m; }
    else if (f < 6)  { src = W1; N = 64;  k0 = q * 8;                      col = (f - 2) * 16 + m; }
    else if (f < 22) { int g = f - 6;  src = W2; N = 128; k0 = (g >> 3) * 32 + q * 8;      col = (g & 7) * 16 + m; }
    else if (f < 26) { src = W1; N = 64;  k0 = 32 + q * 8;                 col = (f - 22) * 16 + m; }
    else             { int g = f - 26; src = W2; N = 128; k0 = 64 + (g >> 3) * 32 + q * 8; col = (g & 7) * 16 + m; }
    float e[8];
    #pragma unroll
    for (int j = 0; j < 8; j++) e[j] = src[(k0 + j) * N + col];
    uint4 o;
    o.x = packbf(e[0], e[1]); o.y = packbf(e[2], e[3]);
    o.z = packbf(e[4], e[5]); o.w = packbf(e[6], e[7]);
    wpack[f * 64 + L] = o;
}

// ---------------------------------------------------------------------------
// vn_mlp: one poly per block, 4 waves, each wave owns a 16-row slice.
// ALL matmul work (incl. the uniform agg@W_bottom concat term) is MFMA:
// the agg term uses an A-fragment whose 16 rows are all the (bf16) agg
// vector, read with one ds_read_b128 from aggXbf. No scalar au loops.
// MFMA 16x16x32 bf16; C/D: col=lane&15, row=(lane>>4)*4+reg (m89);
// A: A[m=lane&15][k=(lane>>4)*8+j] (m120).
// ---------------------------------------------------------------------------
__global__ __launch_bounds__(256, 4) void vn_mlp(
    const float* __restrict__ data, const uint4* __restrict__ wpack,
    const float* __restrict__ b0, const float* __restrict__ g0, const float* __restrict__ be0,
    const float* __restrict__ b1, const float* __restrict__ g1, const float* __restrict__ be1,
    const float* __restrict__ b2, const float* __restrict__ g2, const float* __restrict__ be2,
    float* __restrict__ Ph)
{
    __shared__ __align__(16) unsigned short hbuf[64 * 72];   // rows wave-private
    __shared__ float agg0p[4][32];
    __shared__ float agg1p[4][64];
    __shared__ float agg2p[4][128];
    __shared__ __align__(16) unsigned short agg0bf[32];
    __shared__ __align__(16) unsigned short agg1bf[64];

    const int tid = threadIdx.x;
    const int w = tid >> 6, L = tid & 63, q = L >> 4, m = L & 15;
    const int blk = blockIdx.x;              // b*NPOLY + p
    const int bb = blk >> 8, pp = blk & 255;

    // ---------------- layer 0 : 32 -> 32 (rows w*16 .. w*16+15) ----------
    bf16x8 A0;
    {
        const float* rp = data + ((size_t)bb * NV + 1 + (size_t)pp * VPP + w * 16 + m) * LCH + q * 8;
        float4 u = *(const float4*)rp;
        float4 v = *(const float4*)(rp + 4);
        if (q == 3) v.w = 0.f;               // vecs[:, :, -1] = 0
        U4B8 c;
        c.u.x = packbf(u.x, u.y); c.u.y = packbf(u.z, u.w);
        c.u.z = packbf(v.x, v.y); c.u.w = packbf(v.z, v.w);
        A0 = c.v;
    }
    f32x4 acc0[2];
    {
        U4B8 t0, t1; t0.u = wpack[0 * 64 + L]; t1.u = wpack[1 * 64 + L];
        float b00 = b0[m], b01 = b0[16 + m];
        f32x4 ai0 = { b00, b00, b00, b00 };
        f32x4 ai1 = { b01, b01, b01, b01 };
        acc0[0] = __builtin_amdgcn_mfma_f32_16x16x32_bf16(A0, t0.v, ai0, 0, 0, 0);
        acc0[1] = __builtin_amdgcn_mfma_f32_16x16x32_bf16(A0, t1.v, ai1, 0, 0, 0);
    }
    {
        float g0c[2]  = { g0[m],  g0[16 + m]  };
        float be0c[2] = { be0[m], be0[16 + m] };
        float mx[2] = { 0.f, 0.f };
        #pragma unroll
        for (int reg = 0; reg < 4; reg++) {
            float x0 = acc0[0][reg], x1 = acc0[1][reg];
            float rs = x0 + x1, rq = x0 * x0 + x1 * x1;
            #pragma unroll
            for (int s = 1; s < 16; s <<= 1) { rs += __shfl_xor(rs, s, 64); rq += __shfl_xor(rq, s, 64); }
            float mu = rs * (1.f / 32.f);
            float var = rq * (1.f / 32.f) - mu * mu;
            float ri = rsqrtf(var + LN_EPS);
            #pragma unroll
            for (int ct = 0; ct < 2; ct++) {
                float v = fmaxf(fmaf(g0c[ct] * ri, acc0[ct][reg] - mu, be0c[ct]), 0.f);
                acc0[ct][reg] = v;
                mx[ct] = fmaxf(mx[ct], v);
            }
        }
        #pragma unroll
        for (int ct = 0; ct < 2; ct++) {
            float v = mx[ct];
            v = fmaxf(v, __shfl_xor(v, 16, 64));
            v = fmaxf(v, __shfl_xor(v, 32, 64));
            mx[ct] = v;
        }
        if (q == 0) { agg0p[w][m] = mx[0]; agg0p[w][16 + m] = mx[1]; }
        #pragma unroll
        for (int reg = 0; reg < 4; reg++) {
            int row = w * 16 + q * 4 + reg;
            hbuf[row * 72 + m]      = (unsigned short)f2bf_u(acc0[0][reg]);
            hbuf[row * 72 + 16 + m] = (unsigned short)f2bf_u(acc0[1][reg]);
        }
    }
    __syncthreads();
    // cross-wave agg0 max -> bf16 broadcast buffer
    if (tid < 32) {
        float a = fmaxf(fmaxf(agg0p[0][tid], agg0p[1][tid]),
                        fmaxf(agg0p[2][tid], agg0p[3][tid]));
        agg0bf[tid] = (unsigned short)f2bf_u(a);
    }
    __syncthreads();

    // ---------------- layer 1 : 64 -> 64 (agg term via MFMA) --------------
    bf16x8 A1, Ag0;
    { U4B8 c; c.u = *(const uint4*)(hbuf + (w * 16 + m) * 72 + q * 8); A1 = c.v; }
    { U4B8 c; c.u = *(const uint4*)(agg0bf + q * 8); Ag0 = c.v; }
    f32x4 acc1[4];
    #pragma unroll
    for (int ct = 0; ct < 4; ct++) {
        U4B8 wt, wb;
        wt.u = wpack[(2 + ct) * 64 + L];
        wb.u = wpack[(22 + ct) * 64 + L];
        float bi = b1[ct * 16 + m];
        f32x4 ai = { bi, bi, bi, bi };
        ai = __builtin_amdgcn_mfma_f32_16x16x32_bf16(Ag0, wb.v, ai, 0, 0, 0);
        ai = __builtin_amdgcn_mfma_f32_16x16x32_bf16(A1,  wt.v, ai, 0, 0, 0);
        acc1[ct] = ai;
    }
    {
        float g1c[4], be1c[4];
        #pragma unroll
        for (int ct = 0; ct < 4; ct++) { g1c[ct] = g1[ct * 16 + m]; be1c[ct] = be1[ct * 16 + m]; }
        float mx[4] = { 0.f, 0.f, 0.f, 0.f };
        #pragma unroll
        for (int reg = 0; reg < 4; reg++) {
            float rs = 0.f, rq = 0.f;
            #pragma unroll
            for (int ct = 0; ct < 4; ct++) { float x = acc1[ct][reg]; rs += x; rq += x * x; }
            #pragma unroll
            for (int s = 1; s < 16; s <<= 1) { rs += __shfl_xor(rs, s, 64); rq += __shfl_xor(rq, s, 64); }
            float mu = rs * (1.f / 64.f);
            float var = rq * (1.f / 64.f) - mu * mu;
            float ri = rsqrtf(var + LN_EPS);
            #pragma unroll
            for (int ct = 0; ct < 4; ct++) {
                float v = fmaxf(fmaf(g1c[ct] * ri, acc1[ct][reg] - mu, be1c[ct]), 0.f);
                acc1[ct][reg] = v;
                mx[ct] = fmaxf(mx[ct], v);
            }
        }
        #pragma unroll
        for (int ct = 0; ct < 4; ct++) {
            float v = mx[ct];
            v = fmaxf(v, __shfl_xor(v, 16, 64));
            v = fmaxf(v, __shfl_xor(v, 32, 64));
            mx[ct] = v;
        }
        if (q == 0) {
            #pragma unroll
            for (int ct = 0; ct < 4; ct++) agg1p[w][ct * 16 + m] = mx[ct];
        }
        #pragma unroll
        for (int reg = 0; reg < 4; reg++) {
            int row = w * 16 + q * 4 + reg;
            #pragma unroll
            for (int ct = 0; ct < 4; ct++)
                hbuf[row * 72 + ct * 16 + m] = (unsigned short)f2bf_u(acc1[ct][reg]);
        }
    }
    __syncthreads();
    if (tid < 64) {
        float a = fmaxf(fmaxf(agg1p[0][tid], agg1p[1][tid]),
                        fmaxf(agg1p[2][tid], agg1p[3][tid]));
        agg1bf[tid] = (unsigned short)f2bf_u(a);
    }
    __syncthreads();

    // ---------------- layer 2 : 128 -> 128 (agg term via MFMA) ------------
    bf16x8 A2[2], Ag1[2];
    #pragma unroll
    for (int ks = 0; ks < 2; ks++) {
        { U4B8 c; c.u = *(const uint4*)(hbuf + (w * 16 + m) * 72 + ks * 32 + q * 8); A2[ks] = c.v; }
        { U4B8 c; c.u = *(const uint4*)(agg1bf + ks * 32 + q * 8); Ag1[ks] = c.v; }
    }
    f32x4 acc2[8];
    #pragma unroll
    for (int ct = 0; ct < 8; ct++) {
        U4B8 wt0, wt1, wb0, wb1;
        wt0.u = wpack[(6 + ct) * 64 + L];
        wt1.u = wpack[(14 + ct) * 64 + L];
        wb0.u = wpack[(26 + ct) * 64 + L];
        wb1.u = wpack[(34 + ct) * 64 + L];
        float bi = b2[ct * 16 + m];
        f32x4 ai = { bi, bi, bi, bi };
        ai = __builtin_amdgcn_mfma_f32_16x16x32_bf16(Ag1[0], wb0.v, ai, 0, 0, 0);
        ai = __builtin_amdgcn_mfma_f32_16x16x32_bf16(Ag1[1], wb1.v, ai, 0, 0, 0);
        ai = __builtin_amdgcn_mfma_f32_16x16x32_bf16(A2[0],  wt0.v, ai, 0, 0, 0);
        ai = __builtin_amdgcn_mfma_f32_16x16x32_bf16(A2[1],  wt1.v, ai, 0, 0, 0);
        acc2[ct] = ai;
    }
    {
        float g2c[8], be2c[8];
        #pragma unroll
        for (int ct = 0; ct < 8; ct++) { g2c[ct] = g2[ct * 16 + m]; be2c[ct] = be2[ct * 16 + m]; }
        float mx[8] = { 0.f, 0.f, 0.f, 0.f, 0.f, 0.f, 0.f, 0.f };
        #pragma unroll
        for (int reg = 0; reg < 4; reg++) {
            float rs = 0.f, rq = 0.f;
            #pragma unroll
            for (int ct = 0; ct < 8; ct++) { float x = acc2[ct][reg]; rs += x; rq += x * x; }
            #pragma unroll
            for (int s = 1; s < 16; s <<= 1) { rs += __shfl_xor(rs, s, 64); rq += __shfl_xor(rq, s, 64); }
            float mu = rs * (1.f / 128.f);
            float var = rq * (1.f / 128.f) - mu * mu;
            float ri = rsqrtf(var + LN_EPS);
            #pragma unroll
            for (int ct = 0; ct < 8; ct++) {
                float v = fmaxf(fmaf(g2c[ct] * ri, acc2[ct][reg] - mu, be2c[ct]), 0.f);
                mx[ct] = fmaxf(mx[ct], v);
            }
        }
        #pragma unroll
        for (int ct = 0; ct < 8; ct++) {
            float v = mx[ct];
            v = fmaxf(v, __shfl_xor(v, 16, 64));
            v = fmaxf(v, __shfl_xor(v, 32, 64));
            mx[ct] = v;
        }
        if (q == 0) {
            #pragma unroll
            for (int ct = 0; ct < 8; ct++) agg2p[w][ct * 16 + m] = mx[ct];
        }
    }
    __syncthreads();

    // final col-max across waves; wave w writes cols [w*32, w*32+32)
    if (L < 32) {
        int col = w * 32 + L;
        float v = fmaxf(fmaxf(agg2p[0][col], agg2p[1][col]),
                        fmaxf(agg2p[2][col], agg2p[3][col]));
        Ph[(size_t)blk * 128 + col] = v;
    }
}

// ---------------------------------------------------------------------------
// vn_attn: per-batch tail on folded matrices.
//   q = pah @ Wqf + bq ; tts[j] = q . Wkf[j] ; scores = Ph . tts / 16 ;
//   softmax ; out = (sum att*Ph) @ Wvf + bv
// ---------------------------------------------------------------------------
__global__ __launch_bounds__(256) void vn_attn(
    const float* __restrict__ data, const float* __restrict__ Ph,
    const float* __restrict__ Wqf, const float* __restrict__ Wkf,
    const float* __restrict__ Wvf, const float* __restrict__ bq,
    const float* __restrict__ bv, float* __restrict__ out)
{
    __shared__ float pah[128], qs[256], tts[128], sc[256], pb[128], red[8];
    const int b = blockIdx.x, tid = threadIdx.x, lane = tid & 63, wave = tid >> 6;
    const float* PhB = Ph + (size_t)b * NPOLY * 128;
    const int agent = (int)data[(size_t)b * NV * LCH];

    if (tid < 128) pah[tid] = PhB[(size_t)agent * 128 + tid];
    __syncthreads();
    {
        float a = bq[tid];
        for (int i = 0; i < 128; i++) a = fmaf(pah[i], Wqf[i * 256 + tid], a);
        qs[tid] = a;
    }
    __syncthreads();
    for (int jj = 0; jj < 32; jj++) {
        const int j = wave * 32 + jj;
        const float* wr = Wkf + (size_t)j * 256;
        float p = wr[lane] * qs[lane];
        p = fmaf(wr[ 64 + lane], qs[ 64 + lane], p);
        p = fmaf(wr[128 + lane], qs[128 + lane], p);
        p = fmaf(wr[192 + lane], qs[192 + lane], p);
        #pragma unroll
        for (int s = 1; s < 64; s <<= 1) p += __shfl_xor(p, s, 64);
        if (lane == 0) tts[j] = p;
    }
    __syncthreads();
    for (int pi = 0; pi < 64; pi++) {
        const int p = wave * 64 + pi;
        const float* pr = PhB + (size_t)p * 128;
        float s = pr[lane] * tts[lane];
        s = fmaf(pr[64 + lane], tts[64 + lane], s);
        #pragma unroll
        for (int st = 1; st < 64; st <<= 1) s += __shfl_xor(s, st, 64);
        if (lane == 0) sc[p] = s * 0.0625f;
    }
    __syncthreads();
    float sv = sc[tid];
    float mx = sv;
    #pragma unroll
    for (int s = 1; s < 64; s <<= 1) mx = fmaxf(mx, __shfl_xor(mx, s, 64));
    if (lane == 0) red[wave] = mx;
    __syncthreads();
    mx = fmaxf(fmaxf(red[0], red[1]), fmaxf(red[2], red[3]));
    float e = expf(sv - mx);
    float sm = e;
    #pragma unroll
    for (int s = 1; s < 64; s <<= 1) sm += __shfl_xor(sm, s, 64);
    if (lane == 0) red[4 + wave] = sm;
    __syncthreads();
    const float tot = red[4] + red[5] + red[6] + red[7];
    sc[tid] = e / tot;
    __syncthreads();
    if (tid < 128) {
        float a = 0.f;
        for (int p = 0; p < 256; p++) a = fmaf(sc[p], PhB[(size_t)p * 128 + tid], a);
        pb[tid] = a;
    }
    __syncthreads();
    float o = bv[tid];
    for (int j = 0; j < 128; j++) o = fmaf(pb[j], Wvf[j * 256 + tid], o);
    out[(size_t)b * 256 + tid] = o;
}

extern "C" void kernel_launch(void* const* d_in, const int* in_sizes, int n_in,
                              void* d_out, int out_size, void* d_ws, size_t ws_size,
                              hipStream_t stream)
{
    const float* data = (const float*)d_in[0];
    const float* W0 = (const float*)d_in[1];
    const float* b0 = (const float*)d_in[2];
    const float* g0 = (const float*)d_in[3];
    const float* be0= (const float*)d_in[4];
    const float* W1 = (const float*)d_in[5];
    const float* b1 = (const float*)d_in[6];
    const float* g1 = (const float*)d_in[7];
    const float* be1= (const float*)d_in[8];
    const float* W2 = (const float*)d_in[9];
    const float* b2 = (const float*)d_in[10];
    const float* g2 = (const float*)d_in[11];
    const float* be2= (const float*)d_in[12];
    const float* Wq = (const float*)d_in[13];
    const float* bq = (const float*)d_in[14];
    const float* Wk = (const float*)d_in[15];
    const float* bk = (const float*)d_in[16];
    const float* Wv = (const float*)d_in[17];
    const float* bv = (const float*)d_in[18];
    (void)bk;

    char* wsb = (char*)d_ws;
    float* Ph    = (float*)(wsb);                  // 4 MB
    float* Wqf   = (float*)(wsb + 4194304);        // 128 KB
    float* Wkf   = (float*)(wsb + 4325376);        // 128 KB
    float* Wvf   = (float*)(wsb + 4456448);        // 128 KB
    uint4* wpack = (uint4*)(wsb + 4587520);        // 42 KB

    vn_prep1<<<395, 256, 0, stream>>>(W0, W1, W2, Wq, Wk, Wv, Wqf, Wkf, Wvf, wpack);
    vn_mlp<<<8192, 256, 0, stream>>>(data, wpack,
                                     b0, g0, be0,
                                     b1, g1, be1,
                                     b2, g2, be2, Ph);
    vn_attn<<<32, 256, 0, stream>>>(data, Ph, Wqf, Wkf, Wvf, bq, bv, (float*)d_out);
}

// Round 6
// 251.117 us; speedup vs baseline: 1.1469x; 1.0109x over previous
//
#include <hip/hip_runtime.h>
#include <hip/hip_bf16.h>

#define NPOLY 256
#define VPP   64
#define LCH   32
#define NV    (1 + NPOLY * VPP)
#define LN_EPS 1e-5f

typedef __bf16 bf16x8 __attribute__((ext_vector_type(8)));
typedef float  f32x4  __attribute__((ext_vector_type(4)));

union U4B8 { uint4 u; bf16x8 v; };

__device__ __forceinline__ unsigned f2bf_u(float f) {
    unsigned u = __float_as_uint(f);
    return (u + 0x7FFFu + ((u >> 16) & 1u)) >> 16;   // RNE fp32 -> bf16 bits
}
__device__ __forceinline__ unsigned packbf(float a, float b) {
    return f2bf_u(a) | (f2bf_u(b) << 16);
}
// packed pair conversion — lowers to v_cvt_pk_bf16_f32 where available
__device__ __forceinline__ unsigned packbf2(float a, float b) {
    union { __hip_bfloat162 h; unsigned u; } c;
    float2 f; f.x = a; f.y = b;
    c.h = __float22bfloat162_rn(f);
    return c.u;
}

// ---------------------------------------------------------------------------
// prep1: (a) fold Wq/Wk/Wv over the duplicated 128-channel halves of P,
//        (b) pack weights into bf16 B-fragment order:
//        frag f, lane L: 8 bf16 = W[k0 + j][col], col = ct*16 + (L&15),
//        k0 = (L>>4)*8 (+32*ks) (+row offset for bottom halves).
//        Frags: 0-1 W0 | 2-5 W1top | 6-21 W2top(ks,ct) | 22-25 W1bot |
//               26-41 W2bot(ks,ct)
// ---------------------------------------------------------------------------
__global__ void vn_prep1(const float* __restrict__ W0, const float* __restrict__ W1,
                         const float* __restrict__ W2,
                         const float* __restrict__ Wq, const float* __restrict__ Wk,
                         const float* __restrict__ Wv,
                         float* __restrict__ Wqf, float* __restrict__ Wkf,
                         float* __restrict__ Wvf, uint4* __restrict__ wpack)
{
    int t = blockIdx.x * 256 + threadIdx.x;
    if (t < 3 * 32768) {
        int which = t >> 15, r = t & 32767;    // r = i*256+c, i<128
        const float* src = which == 0 ? Wq : which == 1 ? Wk : Wv;
        float*       dst = which == 0 ? Wqf : which == 1 ? Wkf : Wvf;
        dst[r] = src[r] + src[r + 128 * 256];
        return;
    }
    t -= 3 * 32768;
    if (t >= 42 * 64) return;
    int f = t >> 6, L = t & 63, q = L >> 4, m = L & 15;
    const float* src; int N, k0, col;
    if (f < 2)       { src = W0; N = 32;  k0 = q * 8;                      col = f * 16 + m; }
    else if (f < 6)  { src = W1; N = 64;  k0 = q * 8;                      col = (f - 2) * 16 + m; }
    else if (f < 22) { int g = f - 6;  src = W2; N = 128; k0 = (g >> 3) * 32 + q * 8;      col = (g & 7) * 16 + m; }
    else if (f < 26) { src = W1; N = 64;  k0 = 32 + q * 8;                 col = (f - 22) * 16 + m; }
    else             { int g = f - 26; src = W2; N = 128; k0 = 64 + (g >> 3) * 32 + q * 8; col = (g & 7) * 16 + m; }
    float e[8];
    #pragma unroll
    for (int j = 0; j < 8; j++) e[j] = src[(k0 + j) * N + col];
    uint4 o;
    o.x = packbf(e[0], e[1]); o.y = packbf(e[2], e[3]);
    o.z = packbf(e[4], e[5]); o.w = packbf(e[6], e[7]);
    wpack[f * 64 + L] = o;
}

// ---------------------------------------------------------------------------
// vn_mlp: one poly per block, 4 waves, each wave owns a 16-row slice.
// All matmul work (incl. the uniform agg@W_bottom concat term) is MFMA.
// launch_bounds(256,8): VGPR<=64 so 8 waves/SIMD can be resident —
// the serial MFMA->LN->pack->LDS chain needs TLP to hide.
// MFMA 16x16x32 bf16; C/D: col=lane&15, row=(lane>>4)*4+reg (m89);
// A: A[m=lane&15][k=(lane>>4)*8+j] (m120).
// ---------------------------------------------------------------------------
__global__ __launch_bounds__(256, 8) void vn_mlp(
    const float* __restrict__ data, const uint4* __restrict__ wpack,
    const float* __restrict__ b0, const float* __restrict__ g0, const float* __restrict__ be0,
    const float* __restrict__ b1, const float* __restrict__ g1, const float* __restrict__ be1,
    const float* __restrict__ b2, const float* __restrict__ g2, const float* __restrict__ be2,
    float* __restrict__ Ph)
{
    __shared__ __align__(16) unsigned short hbuf[64 * 72];   // rows wave-private
    __shared__ float agg0p[4][32];
    __shared__ float agg1p[4][64];
    __shared__ float agg2p[4][128];
    __shared__ __align__(16) unsigned short agg0bf[32];
    __shared__ __align__(16) unsigned short agg1bf[64];

    const int tid = threadIdx.x;
    const int w = tid >> 6, L = tid & 63, q = L >> 4, m = L & 15;
    const int blk = blockIdx.x;              // b*NPOLY + p
    const int bb = blk >> 8, pp = blk & 255;

    // ---------------- layer 0 : 32 -> 32 (rows w*16 .. w*16+15) ----------
    bf16x8 A0;
    {
        const float* rp = data + ((size_t)bb * NV + 1 + (size_t)pp * VPP + w * 16 + m) * LCH + q * 8;
        float4 u = *(const float4*)rp;
        float4 v = *(const float4*)(rp + 4);
        if (q == 3) v.w = 0.f;               // vecs[:, :, -1] = 0
        U4B8 c;
        c.u.x = packbf2(u.x, u.y); c.u.y = packbf2(u.z, u.w);
        c.u.z = packbf2(v.x, v.y); c.u.w = packbf2(v.z, v.w);
        A0 = c.v;
    }
    f32x4 acc0[2];
    {
        U4B8 t0, t1; t0.u = wpack[0 * 64 + L]; t1.u = wpack[1 * 64 + L];
        float b00 = b0[m], b01 = b0[16 + m];
        f32x4 ai0 = { b00, b00, b00, b00 };
        f32x4 ai1 = { b01, b01, b01, b01 };
        acc0[0] = __builtin_amdgcn_mfma_f32_16x16x32_bf16(A0, t0.v, ai0, 0, 0, 0);
        acc0[1] = __builtin_amdgcn_mfma_f32_16x16x32_bf16(A0, t1.v, ai1, 0, 0, 0);
    }
    {
        float g0c[2]  = { g0[m],  g0[16 + m]  };
        float be0c[2] = { be0[m], be0[16 + m] };
        float mx[2] = { 0.f, 0.f };
        #pragma unroll
        for (int reg = 0; reg < 4; reg++) {
            float x0 = acc0[0][reg], x1 = acc0[1][reg];
            float rs = x0 + x1, rq = fmaf(x0, x0, x1 * x1);
            #pragma unroll
            for (int s = 1; s < 16; s <<= 1) { rs += __shfl_xor(rs, s, 64); rq += __shfl_xor(rq, s, 64); }
            float mu = rs * (1.f / 32.f);
            float var = rq * (1.f / 32.f) - mu * mu;
            float ri = rsqrtf(var + LN_EPS);
            #pragma unroll
            for (int ct = 0; ct < 2; ct++) {
                float v = fmaxf(fmaf(g0c[ct] * ri, acc0[ct][reg] - mu, be0c[ct]), 0.f);
                acc0[ct][reg] = v;
                mx[ct] = fmaxf(mx[ct], v);
            }
        }
        #pragma unroll
        for (int ct = 0; ct < 2; ct++) {
            float v = mx[ct];
            v = fmaxf(v, __shfl_xor(v, 16, 64));
            v = fmaxf(v, __shfl_xor(v, 32, 64));
            mx[ct] = v;
        }
        if (q == 0) { agg0p[w][m] = mx[0]; agg0p[w][16 + m] = mx[1]; }
        #pragma unroll
        for (int reg = 0; reg < 4; reg++) {
            int row = w * 16 + q * 4 + reg;
            unsigned pk = packbf2(acc0[0][reg], acc0[1][reg]);
            hbuf[row * 72 + m]      = (unsigned short)pk;
            hbuf[row * 72 + 16 + m] = (unsigned short)(pk >> 16);
        }
    }
    __syncthreads();
    // cross-wave agg0 max -> bf16 broadcast buffer
    if (tid < 32) {
        float a = fmaxf(fmaxf(agg0p[0][tid], agg0p[1][tid]),
                        fmaxf(agg0p[2][tid], agg0p[3][tid]));
        agg0bf[tid] = (unsigned short)f2bf_u(a);
    }
    __syncthreads();

    // ---------------- layer 1 : 64 -> 64 (agg term via MFMA) --------------
    bf16x8 A1, Ag0;
    { U4B8 c; c.u = *(const uint4*)(hbuf + (w * 16 + m) * 72 + q * 8); A1 = c.v; }
    { U4B8 c; c.u = *(const uint4*)(agg0bf + q * 8); Ag0 = c.v; }
    f32x4 acc1[4];
    #pragma unroll
    for (int ct = 0; ct < 4; ct++) {
        U4B8 wt, wb;
        wt.u = wpack[(2 + ct) * 64 + L];
        wb.u = wpack[(22 + ct) * 64 + L];
        float bi = b1[ct * 16 + m];
        f32x4 ai = { bi, bi, bi, bi };
        ai = __builtin_amdgcn_mfma_f32_16x16x32_bf16(Ag0, wb.v, ai, 0, 0, 0);
        ai = __builtin_amdgcn_mfma_f32_16x16x32_bf16(A1,  wt.v, ai, 0, 0, 0);
        acc1[ct] = ai;
    }
    {
        float g1c[4], be1c[4];
        #pragma unroll
        for (int ct = 0; ct < 4; ct++) { g1c[ct] = g1[ct * 16 + m]; be1c[ct] = be1[ct * 16 + m]; }
        float mx[4] = { 0.f, 0.f, 0.f, 0.f };
        #pragma unroll
        for (int reg = 0; reg < 4; reg++) {
            float rs = 0.f, rq = 0.f;
            #pragma unroll
            for (int ct = 0; ct < 4; ct++) { float x = acc1[ct][reg]; rs += x; rq = fmaf(x, x, rq); }
            #pragma unroll
            for (int s = 1; s < 16; s <<= 1) { rs += __shfl_xor(rs, s, 64); rq += __shfl_xor(rq, s, 64); }
            float mu = rs * (1.f / 64.f);
            float var = rq * (1.f / 64.f) - mu * mu;
            float ri = rsqrtf(var + LN_EPS);
            #pragma unroll
            for (int ct = 0; ct < 4; ct++) {
                float v = fmaxf(fmaf(g1c[ct] * ri, acc1[ct][reg] - mu, be1c[ct]), 0.f);
                acc1[ct][reg] = v;
                mx[ct] = fmaxf(mx[ct], v);
            }
        }
        #pragma unroll
        for (int ct = 0; ct < 4; ct++) {
            float v = mx[ct];
            v = fmaxf(v, __shfl_xor(v, 16, 64));
            v = fmaxf(v, __shfl_xor(v, 32, 64));
            mx[ct] = v;
        }
        if (q == 0) {
            #pragma unroll
            for (int ct = 0; ct < 4; ct++) agg1p[w][ct * 16 + m] = mx[ct];
        }
        #pragma unroll
        for (int reg = 0; reg < 4; reg++) {
            int row = w * 16 + q * 4 + reg;
            unsigned pk01 = packbf2(acc1[0][reg], acc1[1][reg]);
            unsigned pk23 = packbf2(acc1[2][reg], acc1[3][reg]);
            hbuf[row * 72 + m]      = (unsigned short)pk01;
            hbuf[row * 72 + 16 + m] = (unsigned short)(pk01 >> 16);
            hbuf[row * 72 + 32 + m] = (unsigned short)pk23;
            hbuf[row * 72 + 48 + m] = (unsigned short)(pk23 >> 16);
        }
    }
    __syncthreads();
    if (tid < 64) {
        float a = fmaxf(fmaxf(agg1p[0][tid], agg1p[1][tid]),
                        fmaxf(agg1p[2][tid], agg1p[3][tid]));
        agg1bf[tid] = (unsigned short)f2bf_u(a);
    }
    __syncthreads();

    // ---------------- layer 2 : 128 -> 128 (agg term via MFMA) ------------
    bf16x8 A2[2], Ag1[2];
    #pragma unroll
    for (int ks = 0; ks < 2; ks++) {
        { U4B8 c; c.u = *(const uint4*)(hbuf + (w * 16 + m) * 72 + ks * 32 + q * 8); A2[ks] = c.v; }
        { U4B8 c; c.u = *(const uint4*)(agg1bf + ks * 32 + q * 8); Ag1[ks] = c.v; }
    }
    f32x4 acc2[8];
    #pragma unroll
    for (int ct = 0; ct < 8; ct++) {
        U4B8 wt0, wt1, wb0, wb1;
        wt0.u = wpack[(6 + ct) * 64 + L];
        wt1.u = wpack[(14 + ct) * 64 + L];
        wb0.u = wpack[(26 + ct) * 64 + L];
        wb1.u = wpack[(34 + ct) * 64 + L];
        float bi = b2[ct * 16 + m];
        f32x4 ai = { bi, bi, bi, bi };
        ai = __builtin_amdgcn_mfma_f32_16x16x32_bf16(Ag1[0], wb0.v, ai, 0, 0, 0);
        ai = __builtin_amdgcn_mfma_f32_16x16x32_bf16(Ag1[1], wb1.v, ai, 0, 0, 0);
        ai = __builtin_amdgcn_mfma_f32_16x16x32_bf16(A2[0],  wt0.v, ai, 0, 0, 0);
        ai = __builtin_amdgcn_mfma_f32_16x16x32_bf16(A2[1],  wt1.v, ai, 0, 0, 0);
        acc2[ct] = ai;
    }
    {
        float g2c[8], be2c[8];
        #pragma unroll
        for (int ct = 0; ct < 8; ct++) { g2c[ct] = g2[ct * 16 + m]; be2c[ct] = be2[ct * 16 + m]; }
        float mx[8] = { 0.f, 0.f, 0.f, 0.f, 0.f, 0.f, 0.f, 0.f };
        #pragma unroll
        for (int reg = 0; reg < 4; reg++) {
            float rs = 0.f, rq = 0.f;
            #pragma unroll
            for (int ct = 0; ct < 8; ct++) { float x = acc2[ct][reg]; rs += x; rq = fmaf(x, x, rq); }
            #pragma unroll
            for (int s = 1; s < 16; s <<= 1) { rs += __shfl_xor(rs, s, 64); rq += __shfl_xor(rq, s, 64); }
            float mu = rs * (1.f / 128.f);
            float var = rq * (1.f / 128.f) - mu * mu;
            float ri = rsqrtf(var + LN_EPS);
            #pragma unroll
            for (int ct = 0; ct < 8; ct++) {
                float v = fmaxf(fmaf(g2c[ct] * ri, acc2[ct][reg] - mu, be2c[ct]), 0.f);
                mx[ct] = fmaxf(mx[ct], v);
            }
        }
        #pragma unroll
        for (int ct = 0; ct < 8; ct++) {
            float v = mx[ct];
            v = fmaxf(v, __shfl_xor(v, 16, 64));
            v = fmaxf(v, __shfl_xor(v, 32, 64));
            mx[ct] = v;
        }
        if (q == 0) {
            #pragma unroll
            for (int ct = 0; ct < 8; ct++) agg2p[w][ct * 16 + m] = mx[ct];
        }
    }
    __syncthreads();

    // final col-max across waves; wave w writes cols [w*32, w*32+32)
    if (L < 32) {
        int col = w * 32 + L;
        float v = fmaxf(fmaxf(agg2p[0][col], agg2p[1][col]),
                        fmaxf(agg2p[2][col], agg2p[3][col]));
        Ph[(size_t)blk * 128 + col] = v;
    }
}

// ---------------------------------------------------------------------------
// vn_attn: per-batch tail on folded matrices.
//   q = pah @ Wqf + bq ; tts[j] = q . Wkf[j] ; scores = Ph . tts / 16 ;
//   softmax ; out = (sum att*Ph) @ Wvf + bv
// ---------------------------------------------------------------------------
__global__ __launch_bounds__(256) void vn_attn(
    const float* __restrict__ data, const float* __restrict__ Ph,
    const float* __restrict__ Wqf, const float* __restrict__ Wkf,
    const float* __restrict__ Wvf, const float* __restrict__ bq,
    const float* __restrict__ bv, float* __restrict__ out)
{
    __shared__ float pah[128], qs[256], tts[128], sc[256], pb[128], red[8];
    const int b = blockIdx.x, tid = threadIdx.x, lane = tid & 63, wave = tid >> 6;
    const float* PhB = Ph + (size_t)b * NPOLY * 128;
    const int agent = (int)data[(size_t)b * NV * LCH];

    if (tid < 128) pah[tid] = PhB[(size_t)agent * 128 + tid];
    __syncthreads();
    {
        float a = bq[tid];
        for (int i = 0; i < 128; i++) a = fmaf(pah[i], Wqf[i * 256 + tid], a);
        qs[tid] = a;
    }
    __syncthreads();
    for (int jj = 0; jj < 32; jj++) {
        const int j = wave * 32 + jj;
        const float* wr = Wkf + (size_t)j * 256;
        float p = wr[lane] * qs[lane];
        p = fmaf(wr[ 64 + lane], qs[ 64 + lane], p);
        p = fmaf(wr[128 + lane], qs[128 + lane], p);
        p = fmaf(wr[192 + lane], qs[192 + lane], p);
        #pragma unroll
        for (int s = 1; s < 64; s <<= 1) p += __shfl_xor(p, s, 64);
        if (lane == 0) tts[j] = p;
    }
    __syncthreads();
    for (int pi = 0; pi < 64; pi++) {
        const int p = wave * 64 + pi;
        const float* pr = PhB + (size_t)p * 128;
        float s = pr[lane] * tts[lane];
        s = fmaf(pr[64 + lane], tts[64 + lane], s);
        #pragma unroll
        for (int st = 1; st < 64; st <<= 1) s += __shfl_xor(s, st, 64);
        if (lane == 0) sc[p] = s * 0.0625f;
    }
    __syncthreads();
    float sv = sc[tid];
    float mx = sv;
    #pragma unroll
    for (int s = 1; s < 64; s <<= 1) mx = fmaxf(mx, __shfl_xor(mx, s, 64));
    if (lane == 0) red[wave] = mx;
    __syncthreads();
    mx = fmaxf(fmaxf(red[0], red[1]), fmaxf(red[2], red[3]));
    float e = expf(sv - mx);
    float sm = e;
    #pragma unroll
    for (int s = 1; s < 64; s <<= 1) sm += __shfl_xor(sm, s, 64);
    if (lane == 0) red[4 + wave] = sm;
    __syncthreads();
    const float tot = red[4] + red[5] + red[6] + red[7];
    sc[tid] = e / tot;
    __syncthreads();
    if (tid < 128) {
        float a = 0.f;
        for (int p = 0; p < 256; p++) a = fmaf(sc[p], PhB[(size_t)p * 128 + tid], a);
        pb[tid] = a;
    }
    __syncthreads();
    float o = bv[tid];
    for (int j = 0; j < 128; j++) o = fmaf(pb[j], Wvf[j * 256 + tid], o);
    out[(size_t)b * 256 + tid] = o;
}

extern "C" void kernel_launch(void* const* d_in, const int* in_sizes, int n_in,
                              void* d_out, int out_size, void* d_ws, size_t ws_size,
                              hipStream_t stream)
{
    const float* data = (const float*)d_in[0];
    const float* W0 = (const float*)d_in[1];
    const float* b0 = (const float*)d_in[2];
    const float* g0 = (const float*)d_in[3];
    const float* be0= (const float*)d_in[4];
    const float* W1 = (const float*)d_in[5];
    const float* b1 = (const float*)d_in[6];
    const float* g1 = (const float*)d_in[7];
    const float* be1= (const float*)d_in[8];
    const float* W2 = (const float*)d_in[9];
    const float* b2 = (const float*)d_in[10];
    const float* g2 = (const float*)d_in[11];
    const float* be2= (const float*)d_in[12];
    const float* Wq = (const float*)d_in[13];
    const float* bq = (const float*)d_in[14];
    const float* Wk = (const float*)d_in[15];
    const float* bk = (const float*)d_in[16];
    const float* Wv = (const float*)d_in[17];
    const float* bv = (const float*)d_in[18];
    (void)bk;

    char* wsb = (char*)d_ws;
    float* Ph    = (float*)(wsb);                  // 4 MB
    float* Wqf   = (float*)(wsb + 4194304);        // 128 KB
    float* Wkf   = (float*)(wsb + 4325376);        // 128 KB
    float* Wvf   = (float*)(wsb + 4456448);        // 128 KB
    uint4* wpack = (uint4*)(wsb + 4587520);        // 42 KB

    vn_prep1<<<395, 256, 0, stream>>>(W0, W1, W2, Wq, Wk, Wv, Wqf, Wkf, Wvf, wpack);
    vn_mlp<<<8192, 256, 0, stream>>>(data, wpack,
                                     b0, g0, be0,
                                     b1, g1, be1,
                                     b2, g2, be2, Ph);
    vn_attn<<<32, 256, 0, stream>>>(data, Ph, Wqf, Wkf, Wvf, bq, bv, (float*)d_out);
}

// Round 7
// 239.500 us; speedup vs baseline: 1.2025x; 1.0485x over previous
//
#include <hip/hip_runtime.h>
#include <hip/hip_bf16.h>

#define NPOLY 256
#define VPP   64
#define LCH   32
#define NV    (1 + NPOLY * VPP)
#define LN_EPS 1e-5f

typedef __bf16 bf16x8 __attribute__((ext_vector_type(8)));
typedef float  f32x4  __attribute__((ext_vector_type(4)));

union U4B8 { uint4 u; bf16x8 v; };

__device__ __forceinline__ unsigned f2bf_u(float f) {
    unsigned u = __float_as_uint(f);
    return (u + 0x7FFFu + ((u >> 16) & 1u)) >> 16;   // RNE fp32 -> bf16 bits
}
__device__ __forceinline__ unsigned packbf(float a, float b) {
    return f2bf_u(a) | (f2bf_u(b) << 16);
}
// packed pair conversion — lowers to v_cvt_pk_bf16_f32 where available
__device__ __forceinline__ unsigned packbf2(float a, float b) {
    union { __hip_bfloat162 h; unsigned u; } c;
    float2 f; f.x = a; f.y = b;
    c.h = __float22bfloat162_rn(f);
    return c.u;
}

// ---------------------------------------------------------------------------
// prep1: (a) fold Wq/Wk/Wv over the duplicated 128-channel halves of P,
//        (b) pack weights into bf16 B-fragment order:
//        frag f, lane L: 8 bf16 = W[k0 + j][col], col = ct*16 + (L&15),
//        k0 = (L>>4)*8 (+32*ks) (+row offset for bottom halves).
//        Frags: 0-1 W0 | 2-5 W1top | 6-21 W2top(ks,ct) | 22-25 W1bot |
//               26-41 W2bot(ks,ct)
// ---------------------------------------------------------------------------
__global__ void vn_prep1(const float* __restrict__ W0, const float* __restrict__ W1,
                         const float* __restrict__ W2,
                         const float* __restrict__ Wq, const float* __restrict__ Wk,
                         const float* __restrict__ Wv,
                         float* __restrict__ Wqf, float* __restrict__ Wkf,
                         float* __restrict__ Wvf, uint4* __restrict__ wpack)
{
    int t = blockIdx.x * 256 + threadIdx.x;
    if (t < 3 * 32768) {
        int which = t >> 15, r = t & 32767;    // r = i*256+c, i<128
        const float* src = which == 0 ? Wq : which == 1 ? Wk : Wv;
        float*       dst = which == 0 ? Wqf : which == 1 ? Wkf : Wvf;
        dst[r] = src[r] + src[r + 128 * 256];
        return;
    }
    t -= 3 * 32768;
    if (t >= 42 * 64) return;
    int f = t >> 6, L = t & 63, q = L >> 4, m = L & 15;
    const float* src; int N, k0, col;
    if (f < 2)       { src = W0; N = 32;  k0 = q * 8;                      col = f * 16 + m; }
    else if (f < 6)  { src = W1; N = 64;  k0 = q * 8;                      col = (f - 2) * 16 + m; }
    else if (f < 22) { int g = f - 6;  src = W2; N = 128; k0 = (g >> 3) * 32 + q * 8;      col = (g & 7) * 16 + m; }
    else if (f < 26) { src = W1; N = 64;  k0 = 32 + q * 8;                 col = (f - 22) * 16 + m; }
    else             { int g = f - 26; src = W2; N = 128; k0 = 64 + (g >> 3) * 32 + q * 8; col = (g & 7) * 16 + m; }
    float e[8];
    #pragma unroll
    for (int j = 0; j < 8; j++) e[j] = src[(k0 + j) * N + col];
    uint4 o;
    o.x = packbf(e[0], e[1]); o.y = packbf(e[2], e[3]);
    o.z = packbf(e[4], e[5]); o.w = packbf(e[6], e[7]);
    wpack[f * 64 + L] = o;
}

// ---------------------------------------------------------------------------
// vn_mlp: one poly per block, 4 waves, each wave owns a 16-row slice.
// All matmul work (incl. the uniform agg@W_bottom concat term) is MFMA.
// launch_bounds(256,6): 85-VGPR budget — enough for the acc tiles (no
// scratch spill; bound 8 forced VGPR=32 and spilled 8KB/block to scratch,
// WRITE_SIZE 4->68 MB), while allowing 6 waves/SIMD (75% occupancy cap).
// MFMA 16x16x32 bf16; C/D: col=lane&15, row=(lane>>4)*4+reg (m89);
// A: A[m=lane&15][k=(lane>>4)*8+j] (m120).
// ---------------------------------------------------------------------------
__global__ __launch_bounds__(256, 6) void vn_mlp(
    const float* __restrict__ data, const uint4* __restrict__ wpack,
    const float* __restrict__ b0, const float* __restrict__ g0, const float* __restrict__ be0,
    const float* __restrict__ b1, const float* __restrict__ g1, const float* __restrict__ be1,
    const float* __restrict__ b2, const float* __restrict__ g2, const float* __restrict__ be2,
    float* __restrict__ Ph)
{
    __shared__ __align__(16) unsigned short hbuf[64 * 72];   // rows wave-private
    __shared__ float agg0p[4][32];
    __shared__ float agg1p[4][64];
    __shared__ float agg2p[4][128];
    __shared__ __align__(16) unsigned short agg0bf[32];
    __shared__ __align__(16) unsigned short agg1bf[64];

    const int tid = threadIdx.x;
    const int w = tid >> 6, L = tid & 63, q = L >> 4, m = L & 15;
    const int blk = blockIdx.x;              // b*NPOLY + p
    const int bb = blk >> 8, pp = blk & 255;

    // ---------------- layer 0 : 32 -> 32 (rows w*16 .. w*16+15) ----------
    bf16x8 A0;
    {
        const float* rp = data + ((size_t)bb * NV + 1 + (size_t)pp * VPP + w * 16 + m) * LCH + q * 8;
        float4 u = *(const float4*)rp;
        float4 v = *(const float4*)(rp + 4);
        if (q == 3) v.w = 0.f;               // vecs[:, :, -1] = 0
        U4B8 c;
        c.u.x = packbf2(u.x, u.y); c.u.y = packbf2(u.z, u.w);
        c.u.z = packbf2(v.x, v.y); c.u.w = packbf2(v.z, v.w);
        A0 = c.v;
    }
    f32x4 acc0[2];
    {
        U4B8 t0, t1; t0.u = wpack[0 * 64 + L]; t1.u = wpack[1 * 64 + L];
        float b00 = b0[m], b01 = b0[16 + m];
        f32x4 ai0 = { b00, b00, b00, b00 };
        f32x4 ai1 = { b01, b01, b01, b01 };
        acc0[0] = __builtin_amdgcn_mfma_f32_16x16x32_bf16(A0, t0.v, ai0, 0, 0, 0);
        acc0[1] = __builtin_amdgcn_mfma_f32_16x16x32_bf16(A0, t1.v, ai1, 0, 0, 0);
    }
    {
        float g0c[2]  = { g0[m],  g0[16 + m]  };
        float be0c[2] = { be0[m], be0[16 + m] };
        float mx[2] = { 0.f, 0.f };
        #pragma unroll
        for (int reg = 0; reg < 4; reg++) {
            float x0 = acc0[0][reg], x1 = acc0[1][reg];
            float rs = x0 + x1, rq = fmaf(x0, x0, x1 * x1);
            #pragma unroll
            for (int s = 1; s < 16; s <<= 1) { rs += __shfl_xor(rs, s, 64); rq += __shfl_xor(rq, s, 64); }
            float mu = rs * (1.f / 32.f);
            float var = rq * (1.f / 32.f) - mu * mu;
            float ri = rsqrtf(var + LN_EPS);
            #pragma unroll
            for (int ct = 0; ct < 2; ct++) {
                float v = fmaxf(fmaf(g0c[ct] * ri, acc0[ct][reg] - mu, be0c[ct]), 0.f);
                acc0[ct][reg] = v;
                mx[ct] = fmaxf(mx[ct], v);
            }
        }
        #pragma unroll
        for (int ct = 0; ct < 2; ct++) {
            float v = mx[ct];
            v = fmaxf(v, __shfl_xor(v, 16, 64));
            v = fmaxf(v, __shfl_xor(v, 32, 64));
            mx[ct] = v;
        }
        if (q == 0) { agg0p[w][m] = mx[0]; agg0p[w][16 + m] = mx[1]; }
        #pragma unroll
        for (int reg = 0; reg < 4; reg++) {
            int row = w * 16 + q * 4 + reg;
            unsigned pk = packbf2(acc0[0][reg], acc0[1][reg]);
            hbuf[row * 72 + m]      = (unsigned short)pk;
            hbuf[row * 72 + 16 + m] = (unsigned short)(pk >> 16);
        }
    }
    __syncthreads();
    // cross-wave agg0 max -> bf16 broadcast buffer
    if (tid < 32) {
        float a = fmaxf(fmaxf(agg0p[0][tid], agg0p[1][tid]),
                        fmaxf(agg0p[2][tid], agg0p[3][tid]));
        agg0bf[tid] = (unsigned short)f2bf_u(a);
    }
    __syncthreads();

    // ---------------- layer 1 : 64 -> 64 (agg term via MFMA) --------------
    bf16x8 A1, Ag0;
    { U4B8 c; c.u = *(const uint4*)(hbuf + (w * 16 + m) * 72 + q * 8); A1 = c.v; }
    { U4B8 c; c.u = *(const uint4*)(agg0bf + q * 8); Ag0 = c.v; }
    f32x4 acc1[4];
    #pragma unroll
    for (int ct = 0; ct < 4; ct++) {
        U4B8 wt, wb;
        wt.u = wpack[(2 + ct) * 64 + L];
        wb.u = wpack[(22 + ct) * 64 + L];
        float bi = b1[ct * 16 + m];
        f32x4 ai = { bi, bi, bi, bi };
        ai = __builtin_amdgcn_mfma_f32_16x16x32_bf16(Ag0, wb.v, ai, 0, 0, 0);
        ai = __builtin_amdgcn_mfma_f32_16x16x32_bf16(A1,  wt.v, ai, 0, 0, 0);
        acc1[ct] = ai;
    }
    {
        float g1c[4], be1c[4];
        #pragma unroll
        for (int ct = 0; ct < 4; ct++) { g1c[ct] = g1[ct * 16 + m]; be1c[ct] = be1[ct * 16 + m]; }
        float mx[4] = { 0.f, 0.f, 0.f, 0.f };
        #pragma unroll
        for (int reg = 0; reg < 4; reg++) {
            float rs = 0.f, rq = 0.f;
            #pragma unroll
            for (int ct = 0; ct < 4; ct++) { float x = acc1[ct][reg]; rs += x; rq = fmaf(x, x, rq); }
            #pragma unroll
            for (int s = 1; s < 16; s <<= 1) { rs += __shfl_xor(rs, s, 64); rq += __shfl_xor(rq, s, 64); }
            float mu = rs * (1.f / 64.f);
            float var = rq * (1.f / 64.f) - mu * mu;
            float ri = rsqrtf(var + LN_EPS);
            #pragma unroll
            for (int ct = 0; ct < 4; ct++) {
                float v = fmaxf(fmaf(g1c[ct] * ri, acc1[ct][reg] - mu, be1c[ct]), 0.f);
                acc1[ct][reg] = v;
                mx[ct] = fmaxf(mx[ct], v);
            }
        }
        #pragma unroll
        for (int ct = 0; ct < 4; ct++) {
            float v = mx[ct];
            v = fmaxf(v, __shfl_xor(v, 16, 64));
            v = fmaxf(v, __shfl_xor(v, 32, 64));
            mx[ct] = v;
        }
        if (q == 0) {
            #pragma unroll
            for (int ct = 0; ct < 4; ct++) agg1p[w][ct * 16 + m] = mx[ct];
        }
        #pragma unroll
        for (int reg = 0; reg < 4; reg++) {
            int row = w * 16 + q * 4 + reg;
            unsigned pk01 = packbf2(acc1[0][reg], acc1[1][reg]);
            unsigned pk23 = packbf2(acc1[2][reg], acc1[3][reg]);
            hbuf[row * 72 + m]      = (unsigned short)pk01;
            hbuf[row * 72 + 16 + m] = (unsigned short)(pk01 >> 16);
            hbuf[row * 72 + 32 + m] = (unsigned short)pk23;
            hbuf[row * 72 + 48 + m] = (unsigned short)(pk23 >> 16);
        }
    }
    __syncthreads();
    if (tid < 64) {
        float a = fmaxf(fmaxf(agg1p[0][tid], agg1p[1][tid]),
                        fmaxf(agg1p[2][tid], agg1p[3][tid]));
        agg1bf[tid] = (unsigned short)f2bf_u(a);
    }
    __syncthreads();

    // ---------------- layer 2 : 128 -> 128 (agg term via MFMA) ------------
    bf16x8 A2[2], Ag1[2];
    #pragma unroll
    for (int ks = 0; ks < 2; ks++) {
        { U4B8 c; c.u = *(const uint4*)(hbuf + (w * 16 + m) * 72 + ks * 32 + q * 8); A2[ks] = c.v; }
        { U4B8 c; c.u = *(const uint4*)(agg1bf + ks * 32 + q * 8); Ag1[ks] = c.v; }
    }
    f32x4 acc2[8];
    #pragma unroll
    for (int ct = 0; ct < 8; ct++) {
        U4B8 wt0, wt1, wb0, wb1;
        wt0.u = wpack[(6 + ct) * 64 + L];
        wt1.u = wpack[(14 + ct) * 64 + L];
        wb0.u = wpack[(26 + ct) * 64 + L];
        wb1.u = wpack[(34 + ct) * 64 + L];
        float bi = b2[ct * 16 + m];
        f32x4 ai = { bi, bi, bi, bi };
        ai = __builtin_amdgcn_mfma_f32_16x16x32_bf16(Ag1[0], wb0.v, ai, 0, 0, 0);
        ai = __builtin_amdgcn_mfma_f32_16x16x32_bf16(Ag1[1], wb1.v, ai, 0, 0, 0);
        ai = __builtin_amdgcn_mfma_f32_16x16x32_bf16(A2[0],  wt0.v, ai, 0, 0, 0);
        ai = __builtin_amdgcn_mfma_f32_16x16x32_bf16(A2[1],  wt1.v, ai, 0, 0, 0);
        acc2[ct] = ai;
    }
    {
        float g2c[8], be2c[8];
        #pragma unroll
        for (int ct = 0; ct < 8; ct++) { g2c[ct] = g2[ct * 16 + m]; be2c[ct] = be2[ct * 16 + m]; }
        float mx[8] = { 0.f, 0.f, 0.f, 0.f, 0.f, 0.f, 0.f, 0.f };
        #pragma unroll
        for (int reg = 0; reg < 4; reg++) {
            float rs = 0.f, rq = 0.f;
            #pragma unroll
            for (int ct = 0; ct < 8; ct++) { float x = acc2[ct][reg]; rs += x; rq = fmaf(x, x, rq); }
            #pragma unroll
            for (int s = 1; s < 16; s <<= 1) { rs += __shfl_xor(rs, s, 64); rq += __shfl_xor(rq, s, 64); }
            float mu = rs * (1.f / 128.f);
            float var = rq * (1.f / 128.f) - mu * mu;
            float ri = rsqrtf(var + LN_EPS);
            #pragma unroll
            for (int ct = 0; ct < 8; ct++) {
                float v = fmaxf(fmaf(g2c[ct] * ri, acc2[ct][reg] - mu, be2c[ct]), 0.f);
                mx[ct] = fmaxf(mx[ct], v);
            }
        }
        #pragma unroll
        for (int ct = 0; ct < 8; ct++) {
            float v = mx[ct];
            v = fmaxf(v, __shfl_xor(v, 16, 64));
            v = fmaxf(v, __shfl_xor(v, 32, 64));
            mx[ct] = v;
        }
        if (q == 0) {
            #pragma unroll
            for (int ct = 0; ct < 8; ct++) agg2p[w][ct * 16 + m] = mx[ct];
        }
    }
    __syncthreads();

    // final col-max across waves; wave w writes cols [w*32, w*32+32)
    if (L < 32) {
        int col = w * 32 + L;
        float v = fmaxf(fmaxf(agg2p[0][col], agg2p[1][col]),
                        fmaxf(agg2p[2][col], agg2p[3][col]));
        Ph[(size_t)blk * 128 + col] = v;
    }
}

// ---------------------------------------------------------------------------
// vn_attn: per-batch tail on folded matrices.
//   q = pah @ Wqf + bq ; tts[j] = q . Wkf[j] ; scores = Ph . tts / 16 ;
//   softmax ; out = (sum att*Ph) @ Wvf + bv
// ---------------------------------------------------------------------------
__global__ __launch_bounds__(256) void vn_attn(
    const float* __restrict__ data, const float* __restrict__ Ph,
    const float* __restrict__ Wqf, const float* __restrict__ Wkf,
    const float* __restrict__ Wvf, const float* __restrict__ bq,
    const float* __restrict__ bv, float* __restrict__ out)
{
    __shared__ float pah[128], qs[256], tts[128], sc[256], pb[128], red[8];
    const int b = blockIdx.x, tid = threadIdx.x, lane = tid & 63, wave = tid >> 6;
    const float* PhB = Ph + (size_t)b * NPOLY * 128;
    const int agent = (int)data[(size_t)b * NV * LCH];

    if (tid < 128) pah[tid] = PhB[(size_t)agent * 128 + tid];
    __syncthreads();
    {
        float a = bq[tid];
        for (int i = 0; i < 128; i++) a = fmaf(pah[i], Wqf[i * 256 + tid], a);
        qs[tid] = a;
    }
    __syncthreads();
    for (int jj = 0; jj < 32; jj++) {
        const int j = wave * 32 + jj;
        const float* wr = Wkf + (size_t)j * 256;
        float p = wr[lane] * qs[lane];
        p = fmaf(wr[ 64 + lane], qs[ 64 + lane], p);
        p = fmaf(wr[128 + lane], qs[128 + lane], p);
        p = fmaf(wr[192 + lane], qs[192 + lane], p);
        #pragma unroll
        for (int s = 1; s < 64; s <<= 1) p += __shfl_xor(p, s, 64);
        if (lane == 0) tts[j] = p;
    }
    __syncthreads();
    for (int pi = 0; pi < 64; pi++) {
        const int p = wave * 64 + pi;
        const float* pr = PhB + (size_t)p * 128;
        float s = pr[lane] * tts[lane];
        s = fmaf(pr[64 + lane], tts[64 + lane], s);
        #pragma unroll
        for (int st = 1; st < 64; st <<= 1) s += __shfl_xor(s, st, 64);
        if (lane == 0) sc[p] = s * 0.0625f;
    }
    __syncthreads();
    float sv = sc[tid];
    float mx = sv;
    #pragma unroll
    for (int s = 1; s < 64; s <<= 1) mx = fmaxf(mx, __shfl_xor(mx, s, 64));
    if (lane == 0) red[wave] = mx;
    __syncthreads();
    mx = fmaxf(fmaxf(red[0], red[1]), fmaxf(red[2], red[3]));
    float e = expf(sv - mx);
    float sm = e;
    #pragma unroll
    for (int s = 1; s < 64; s <<= 1) sm += __shfl_xor(sm, s, 64);
    if (lane == 0) red[4 + wave] = sm;
    __syncthreads();
    const float tot = red[4] + red[5] + red[6] + red[7];
    sc[tid] = e / tot;
    __syncthreads();
    if (tid < 128) {
        float a = 0.f;
        for (int p = 0; p < 256; p++) a = fmaf(sc[p], PhB[(size_t)p * 128 + tid], a);
        pb[tid] = a;
    }
    __syncthreads();
    float o = bv[tid];
    for (int j = 0; j < 128; j++) o = fmaf(pb[j], Wvf[j * 256 + tid], o);
    out[(size_t)b * 256 + tid] = o;
}

extern "C" void kernel_launch(void* const* d_in, const int* in_sizes, int n_in,
                              void* d_out, int out_size, void* d_ws, size_t ws_size,
                              hipStream_t stream)
{
    const float* data = (const float*)d_in[0];
    const float* W0 = (const float*)d_in[1];
    const float* b0 = (const float*)d_in[2];
    const float* g0 = (const float*)d_in[3];
    const float* be0= (const float*)d_in[4];
    const float* W1 = (const float*)d_in[5];
    const float* b1 = (const float*)d_in[6];
    const float* g1 = (const float*)d_in[7];
    const float* be1= (const float*)d_in[8];
    const float* W2 = (const float*)d_in[9];
    const float* b2 = (const float*)d_in[10];
    const float* g2 = (const float*)d_in[11];
    const float* be2= (const float*)d_in[12];
    const float* Wq = (const float*)d_in[13];
    const float* bq = (const float*)d_in[14];
    const float* Wk = (const float*)d_in[15];
    const float* bk = (const float*)d_in[16];
    const float* Wv = (const float*)d_in[17];
    const float* bv = (const float*)d_in[18];
    (void)bk;

    char* wsb = (char*)d_ws;
    float* Ph    = (float*)(wsb);                  // 4 MB
    float* Wqf   = (float*)(wsb + 4194304);        // 128 KB
    float* Wkf   = (float*)(wsb + 4325376);        // 128 KB
    float* Wvf   = (float*)(wsb + 4456448);        // 128 KB
    uint4* wpack = (uint4*)(wsb + 4587520);        // 42 KB

    vn_prep1<<<395, 256, 0, stream>>>(W0, W1, W2, Wq, Wk, Wv, Wqf, Wkf, Wvf, wpack);
    vn_mlp<<<8192, 256, 0, stream>>>(data, wpack,
                                     b0, g0, be0,
                                     b1, g1, be1,
                                     b2, g2, be2, Ph);
    vn_attn<<<32, 256, 0, stream>>>(data, Ph, Wqf, Wkf, Wvf, bq, bv, (float*)d_out);
}